// Round 1
// baseline (2257.496 us; speedup 1.0000x reference)
//
#include <hip/hip_runtime.h>
#include <hip/hip_bf16.h>

// LCA layer on MI355X — rank-factored steps, pipelined counted-vmcnt GEMM core.
//   b = x@W ; g[j] = sum_k W[k][j]^2
//   u1 = 0.1 b ; a1 = relu(u1 - 0.1)
//   per step: t = a@W^T ; s = t@W ; u' = 0.9u + 0.1b - 0.1s + 0.1*a*g ; a' = relu(u'-0.1)
//   out = a@W^T (fp32)
// GEMM core (new this round): BM=256 x BN (256 or 128) tile, BK=64, DEPTH-2 LDS ring
// with 1-tile lookahead: stage tile k+2 after the post-compute barrier, wait only
// vmcnt(LPS) at the top (loads for tile k+1 stay in flight across barriers — never
// drain to 0 in the main loop; raw s_barrier so the compiler can't inject the
// vmcnt(0) drain __syncthreads carries). LDS layout [rows][64] bf16 (128B stride)
// with st_16x32 swizzle (byte ^= ((byte>>9)&1)<<5) applied as inverse-swizzled
// GLOBAL source + swizzled ds_read address (global_load_lds dest stays linear).
// s_setprio(1/0) around MFMA clusters. Operand swap retained: lane's 4 acc regs =
// 4 consecutive output cols at one row (vector epilogue).

typedef __bf16 bf16_t;
typedef __bf16 bf16x8 __attribute__((ext_vector_type(8)));
typedef __bf16 bf16x4 __attribute__((ext_vector_type(4)));
typedef float  f32x4  __attribute__((ext_vector_type(4)));

__device__ __forceinline__ void g2lds16(const void* g, void* l) {
    __builtin_amdgcn_global_load_lds(
        (const __attribute__((address_space(1))) void*)g,
        (__attribute__((address_space(3))) void*)l,
        16, 0, 0);
}

template<int N> __device__ __forceinline__ void waitv() {
    if constexpr (N == 0)      asm volatile("s_waitcnt vmcnt(0)" ::: "memory");
    else if constexpr (N == 6) asm volatile("s_waitcnt vmcnt(6)" ::: "memory");
    else if constexpr (N == 8) asm volatile("s_waitcnt vmcnt(8)" ::: "memory");
}

enum { MODE_B = 0, MODE_T = 1, MODE_STEP2 = 2, MODE_OUT = 3 };

// C[m][n] = sum_k A[m][k] * Bt[n][k]  (A:[M][K], Bt:[N][K], bf16, K%64==0).
// Grid: x covers N in BN-tiles, y covers M in 256-tiles.
template<int MODE, int BN>
__global__ __launch_bounds__(512, 2)
void gemm_bt(const bf16_t* __restrict__ A, const bf16_t* __restrict__ Bt,
             int N, int K,
             float*  __restrict__ outF,   // MODE_OUT: final fp32 output
             bf16_t* __restrict__ outH,   // MODE_T: t ; MODE_B/STEP2: a
             bf16_t* __restrict__ bb,     // MODE_B: write b ; MODE_STEP2: read b
             bf16_t* __restrict__ u,      // MODE_B: write u ; MODE_STEP2: rmw u
             const float* __restrict__ g) // MODE_STEP2: diag(W^T W), [N]
{
    constexpr int BM = 256;
    constexpr int WN_WAVES = (BN == 256) ? 4 : 2;  // 2x4 or 4x2 wave grid
    constexpr int WM_WAVES = 8 / WN_WAVES;
    constexpr int WTM = BM / WM_WAVES;             // 128 or 64
    constexpr int WTN = BN / WN_WAVES;             // 64
    constexpr int FM = WTM / 16;                   // 8 or 4
    constexpr int FN = WTN / 16;                   // 4
    constexpr int LPS_A = BM / 64;                 // g2lds issues per A stage = 4
    constexpr int LPS_B = BN / 64;                 // 4 or 2
    constexpr int LPS = LPS_A + LPS_B;             // 8 or 6 -> steady vmcnt

    // ring of 2 BK=64 tiles, [rows][64] bf16 (128B row stride)
    __shared__ __attribute__((aligned(16))) bf16_t As[2 * BM * 64];
    __shared__ __attribute__((aligned(16))) bf16_t Bs[2 * BN * 64];

    const int t  = threadIdx.x;
    const int l  = t & 63;
    const int w  = t >> 6;
    const int wm = (w / WN_WAVES) * WTM;
    const int wn = (w % WN_WAVES) * WTN;

    const int rowA = blockIdx.y * BM;
    const int colB = blockIdx.x * BN;

    // staging: linear LDS dest byte D = q*8192 + t*16 (wave-uniform base + lane*16);
    // source pre-swizzled: L = D ^ (((D>>9)&1)<<5) -> row = q*64 + t/8,
    // col elems = ((t&7)*8) ^ (((t>>5)&1)*16)   [st_16x32 involution]
    const int srow = t >> 3;
    const int scol = ((t & 7) * 8) ^ (((t >> 5) & 1) * 16);
    const bf16_t* gA = A  + (size_t)(rowA + srow) * K + scol;
    const bf16_t* gB = Bt + (size_t)(colB + srow) * K + scol;
    char* lA = (char*)As + t * 16;
    char* lB = (char*)Bs + t * 16;

    f32x4 acc[FM][FN];
#pragma unroll
    for (int i = 0; i < FM; ++i)
#pragma unroll
        for (int j = 0; j < FN; ++j)
#pragma unroll
            for (int r = 0; r < 4; ++r) acc[i][j][r] = 0.f;

    // fragment read (swizzled): lane l wants logical row (wm+i*16+(l&15)),
    // k-elems p*32 + (l>>4)*8 .. +7 ; physical col elems = p*32 + ((l>>4)*8 ^ rowbit2*16)
    const int lrow  = l & 15;
    const int cfrag = ((l >> 4) * 8) ^ (((l >> 2) & 1) * 16);
    const bf16_t* pA0 = As + (wm + lrow) * 64 + cfrag;
    const bf16_t* pB0 = Bs + (wn + lrow) * 64 + cfrag;

    auto STAGE = [&](int kt, int slot) {
        const int k0 = kt * 64;
#pragma unroll
        for (int q = 0; q < LPS_A; ++q)
            g2lds16(gA + (size_t)(q * 64) * K + k0, lA + slot * (BM * 128) + q * 8192);
#pragma unroll
        for (int q = 0; q < LPS_B; ++q)
            g2lds16(gB + (size_t)(q * 64) * K + k0, lB + slot * (BN * 128) + q * 8192);
    };

    const int NK = K >> 6;
    STAGE(0, 0);
    STAGE(1, 1);

    for (int k = 0; k < NK; ++k) {
        // tile k's LPS loads are the oldest outstanding; leave tile k+1's flying.
        if (k + 1 < NK) waitv<LPS>(); else waitv<0>();
        asm volatile("s_barrier" ::: "memory");   // tile k visible to all waves

        const bf16_t* sA = pA0 + (k & 1) * (BM * 64);
        const bf16_t* sB = pB0 + (k & 1) * (BN * 64);
#pragma unroll
        for (int p = 0; p < 2; ++p) {
            bf16x8 af[FM], bfr[FN];
#pragma unroll
            for (int i = 0; i < FM; ++i) af[i]  = *(const bf16x8*)(sA + i * 1024 + p * 32);
#pragma unroll
            for (int j = 0; j < FN; ++j) bfr[j] = *(const bf16x8*)(sB + j * 1024 + p * 32);
            __builtin_amdgcn_s_setprio(1);
#pragma unroll
            for (int i = 0; i < FM; ++i)
#pragma unroll
                for (int j = 0; j < FN; ++j)
                    acc[i][j] = __builtin_amdgcn_mfma_f32_16x16x32_bf16(
                        bfr[j], af[i], acc[i][j], 0, 0, 0);
            __builtin_amdgcn_s_setprio(0);
        }
        asm volatile("s_waitcnt lgkmcnt(0)" ::: "memory");  // all ds_reads retired
        asm volatile("s_barrier" ::: "memory");             // safe to overwrite slot k&1
        if (k + 2 < NK) STAGE(k + 2, k & 1);
    }

    // epilogue (swapped layout): m = rowA+wm+i*16+(l&15), n = colB+wn+j*16+(l>>4)*4+r
    const int m0 = rowA + wm + (l & 15);
    const int n0 = colB + wn + ((l >> 4) * 4);

    f32x4 gvv[FN];
    if constexpr (MODE == MODE_STEP2) {
#pragma unroll
        for (int j = 0; j < FN; ++j) gvv[j] = *(const f32x4*)(g + n0 + j * 16);
    }

#pragma unroll
    for (int i = 0; i < FM; ++i) {
        const int m = m0 + i * 16;
#pragma unroll
        for (int j = 0; j < FN; ++j) {
            const size_t idx = (size_t)m * N + (n0 + j * 16);
            const f32x4 c = acc[i][j];
            if constexpr (MODE == MODE_T) {
                bf16x4 o;
#pragma unroll
                for (int r = 0; r < 4; ++r) o[r] = (bf16_t)c[r];
                *(bf16x4*)(outH + idx) = o;
            } else if constexpr (MODE == MODE_B) {
                bf16x4 ob, ou, oa;
#pragma unroll
                for (int r = 0; r < 4; ++r) {
                    const float un = 0.1f * c[r];       // u1 = 0.1 b (u0=0 => a0=0)
                    ob[r] = (bf16_t)c[r];
                    ou[r] = (bf16_t)un;
                    oa[r] = (bf16_t)fmaxf(un - 0.1f, 0.f);
                }
                *(bf16x4*)(bb   + idx) = ob;
                *(bf16x4*)(u    + idx) = ou;
                *(bf16x4*)(outH + idx) = oa;
            } else if constexpr (MODE == MODE_STEP2) {
                const bf16x4 uv = *(const bf16x4*)(u  + idx);
                const bf16x4 bv = *(const bf16x4*)(bb + idx);
                bf16x4 ou, oa;
#pragma unroll
                for (int r = 0; r < 4; ++r) {
                    const float uo = (float)uv[r];
                    const float ao = fmaxf(uo - 0.1f, 0.f);    // a_old from u_old
                    const float un = 0.9f * uo + 0.1f * (float)bv[r]
                                   - 0.1f * c[r] + 0.1f * ao * gvv[j][r];
                    ou[r] = (bf16_t)un;
                    oa[r] = (bf16_t)fmaxf(un - 0.1f, 0.f);     // a_next (no race)
                }
                *(bf16x4*)(u    + idx) = ou;
                *(bf16x4*)(outH + idx) = oa;
            } else { // MODE_OUT
                *(f32x4*)(outF + idx) = c;
            }
        }
    }
}

__global__ void cast_x_kernel(const float* __restrict__ x, bf16_t* __restrict__ xh, int n) {
    int i = blockIdx.x * 256 + threadIdx.x;
    if (i < n) xh[i] = (bf16_t)x[i];
}

// Wh = bf16(W) [1024][4096] ; WT = bf16(W^T) [4096][1024]
__global__ void prep_w_kernel(const float* __restrict__ W,
                              bf16_t* __restrict__ Wh, bf16_t* __restrict__ WT) {
    int i = blockIdx.x * 256 + threadIdx.x;
    if (i < 1024 * 4096) {
        int k = i >> 12;
        int n = i & 4095;
        bf16_t v = (bf16_t)W[i];
        Wh[i] = v;
        WT[(size_t)n * 1024 + k] = v;
    }
}

// g[j] = sum_k W[k][j]^2
__global__ void prep_g_kernel(const float* __restrict__ W, float* __restrict__ g) {
    int j = blockIdx.x * 256 + threadIdx.x;
    if (j < 4096) {
        float s = 0.f;
        for (int k = 0; k < 1024; ++k) {
            float v = W[(size_t)k * 4096 + j];
            s += v * v;
        }
        g[j] = s;
    }
}

extern "C" void kernel_launch(void* const* d_in, const int* in_sizes, int n_in,
                              void* d_out, int out_size, void* d_ws, size_t ws_size,
                              hipStream_t stream)
{
    const float* x = (const float*)d_in[0];   // [8192][1024]
    const float* W = (const float*)d_in[1];   // [1024][4096]

    // d_out doubles as scratch until the final GEMM writes it:
    //   [0,16MiB): xh (bf16 x) until b-GEMM, then t ; [16MiB,+16KiB): g
    bf16_t* xh = (bf16_t*)d_out;
    bf16_t* tt = (bf16_t*)d_out;
    float*  gd = (float*)((char*)d_out + 16777216);

    char* ws = (char*)d_ws;                   // 208 MiB total (proven footprint)
    bf16_t* a  = (bf16_t*)(ws);               //  64 MiB [8192][4096]
    bf16_t* bb = (bf16_t*)(ws + 67108864);    //  64 MiB [8192][4096]
    bf16_t* u  = (bf16_t*)(ws + 134217728);   //  64 MiB [8192][4096]
    bf16_t* Wh = (bf16_t*)(ws + 201326592);   //   8 MiB [1024][4096]
    bf16_t* WT = (bf16_t*)(ws + 209715200);   //   8 MiB [4096][1024]

    cast_x_kernel<<<8388608 / 256, 256, 0, stream>>>(x, xh, 8388608);
    prep_w_kernel<<<4194304 / 256, 256, 0, stream>>>(W, Wh, WT);
    prep_g_kernel<<<16, 256, 0, stream>>>(W, gd);

    // b = x@W ; u1 = 0.1b ; a1 = relu(u1-0.1).  A=xh, Bt=WT, N=4096, K=1024
    gemm_bt<MODE_B, 256><<<dim3(16, 32), 512, 0, stream>>>(xh, WT, 4096, 1024,
                                                           nullptr, a, bb, u, nullptr);
    // 9 remaining steps: t = a@W^T (BN=128) ; s = t@W fused u/a update (BN=256)
    for (int s = 0; s < 9; ++s) {
        gemm_bt<MODE_T, 128><<<dim3(8, 32), 512, 0, stream>>>(a, Wh, 1024, 4096,
                                                              nullptr, tt, nullptr, nullptr, nullptr);
        gemm_bt<MODE_STEP2, 256><<<dim3(16, 32), 512, 0, stream>>>(tt, WT, 4096, 1024,
                                                                   nullptr, a, bb, u, gd);
    }
    // out = a@W^T : A=a, Bt=Wh, N=1024, K=4096, fp32 into d_out
    gemm_bt<MODE_OUT, 128><<<dim3(8, 32), 512, 0, stream>>>(a, Wh, 1024, 4096,
                                                            (float*)d_out, nullptr, nullptr, nullptr, nullptr);
}

// Round 2
// 2055.774 us; speedup vs baseline: 1.0981x; 1.0981x over previous
//
#include <hip/hip_runtime.h>
#include <hip/hip_bf16.h>

// LCA layer on MI355X — rank-factored steps, m201-style 4-phase/tile pipelined GEMM.
//   b = x@W ; g[j] = sum_k W[k][j]^2
//   u1 = 0.1 b ; a1 = relu(u1 - 0.1)
//   per step: t = a@W^T ; s = t@W ; u' = 0.9u + 0.1b - 0.1s + 0.1*a*g ; a' = relu(u'-0.1)
//   out = a@W^T (fp32)
//
// GEMM core: BM x 256 tile (BM=256 for STEP2/B, BM=128 for T/OUT), BK=64, 8 waves,
// 2-slot LDS ring. Each K-tile = 4 phases; phase = {issue 2 staging loads of tile
// t+1, counted s_waitcnt vmcnt (never 0 in main loop), s_barrier, ds_read one
// operand slice, setprio(1) + 16 MFMA + setprio(0)}. Staging issue order
// B0,A0,B1,A1 matches consumption order (phases = (qi,qj): (0,0),(0,1),(1,1),(1,0))
// so each load has ~4-7 phases of flight. FIFO-derived waits:
//   BM=256 (8 loads/tile): main {6,6,6}, peeled last {4,2,0}
//   BM=128 (6 loads/tile): main {5,4,5}, peeled last {3,1,0}
// LDS [rows][64] bf16 (128B rows) with slot-XOR swizzle byte ^= ((row&7)<<4):
// 16-lane b128 reads spread over all 8 slots = HW minimum (conflict-free).
// Swizzle applied as inverse-permuted GLOBAL source + XOR'd ds_read address
// (global_load_lds dest stays linear — rule 21). Operand swap retained: lane's
// 4 acc regs = 4 consecutive output cols at one row (8B/16B vector epilogue).
// Bijective XCD-chunk swizzle on block index (nwg % 8 == 0 for all grids).

typedef __bf16 bf16_t;
typedef __bf16 bf16x8 __attribute__((ext_vector_type(8)));
typedef __bf16 bf16x4 __attribute__((ext_vector_type(4)));
typedef float  f32x4  __attribute__((ext_vector_type(4)));

__device__ __forceinline__ void g2lds16(const void* g, void* l) {
    __builtin_amdgcn_global_load_lds(
        (const __attribute__((address_space(1))) void*)g,
        (__attribute__((address_space(3))) void*)l,
        16, 0, 0);
}

template<int N> __device__ __forceinline__ void waitv() {
    if constexpr (N == 0) asm volatile("s_waitcnt vmcnt(0)" ::: "memory");
    else if constexpr (N == 1) asm volatile("s_waitcnt vmcnt(1)" ::: "memory");
    else if constexpr (N == 2) asm volatile("s_waitcnt vmcnt(2)" ::: "memory");
    else if constexpr (N == 3) asm volatile("s_waitcnt vmcnt(3)" ::: "memory");
    else if constexpr (N == 4) asm volatile("s_waitcnt vmcnt(4)" ::: "memory");
    else if constexpr (N == 5) asm volatile("s_waitcnt vmcnt(5)" ::: "memory");
    else if constexpr (N == 6) asm volatile("s_waitcnt vmcnt(6)" ::: "memory");
}
__device__ __forceinline__ void bar() { __builtin_amdgcn_s_barrier(); }

template<int n> struct IC { static constexpr int v = n; };

enum { MODE_B = 0, MODE_T = 1, MODE_STEP2 = 2, MODE_OUT = 3 };

// C[m][n] = sum_k A[m][k] * Bt[n][k]  (A:[M][K], Bt:[N][K], bf16, K%64==0).
// Grid: x covers N in 256-tiles, y covers M in BM-tiles. 512 threads.
template<int MODE, int BM>
__global__ __launch_bounds__(512, 2)
void gemm_bt(const bf16_t* __restrict__ A, const bf16_t* __restrict__ Bt,
             int N, int K,
             float*  __restrict__ outF,   // MODE_OUT: final fp32 output
             bf16_t* __restrict__ outH,   // MODE_T: t ; MODE_B/STEP2: a
             bf16_t* __restrict__ bb,     // MODE_B: write b ; MODE_STEP2: read b
             bf16_t* __restrict__ u,      // MODE_B: write u ; MODE_STEP2: rmw u
             const float* __restrict__ g) // MODE_STEP2: diag(W^T W), [N]
{
    constexpr int BN  = 256;
    constexpr int FM  = BM / 32;       // 8 (BM=256) or 4 (BM=128)
    constexpr int FMH = FM / 2;        // fragments per A-slice: 4 or 2
    constexpr int AUH = BM / 128;      // 64-row A units per slice: 2 or 1
    constexpr int ASZ = BM * 128;      // bytes per A slot
    constexpr int BSZ = BN * 128;      // bytes per B slot

    __shared__ __attribute__((aligned(16))) bf16_t As[2 * BM * 64];
    __shared__ __attribute__((aligned(16))) bf16_t Bs[2 * BN * 64];

    const int t = threadIdx.x;
    const int l = t & 63;
    const int w = t >> 6;
    const int wm = (w >> 2) * (BM / 4);   // {0, BM/4}
    const int wn = (w & 3) * 32;          // {0,32,64,96}

    // bijective XCD-chunk swizzle (nwg % 8 == 0 for all our grids)
    const int gx  = gridDim.x;
    const int nwg = gx * gridDim.y;
    const int bid = blockIdx.y * gx + blockIdx.x;
    const int sw  = (bid & 7) * (nwg >> 3) + (bid >> 3);
    const int rowA = (sw / gx) * BM;
    const int colB = (sw % gx) * BN;

    // ---- staging (linear LDS dest, inverse-swizzled global source) ----
    // dest byte within 8KB unit: D = t*16 -> row=t>>3, slot=t&7
    // logical slot = (t&7) ^ (row&7) -> src col elems = that * 8
    const int srow = t >> 3;
    const int scol = (((t & 7) ^ (srow & 7)) << 3);
    const bf16_t* gA = A  + (size_t)(rowA + srow) * K + scol;
    const bf16_t* gB = Bt + (size_t)(colB + srow) * K + scol;
    char* sA = (char*)As + t * 16;
    char* sB = (char*)Bs + t * 16;

    auto stA = [&](int slot, int kt, int uu) {
        g2lds16(gA + (size_t)uu * 64 * K + kt * 64, sA + slot * ASZ + uu * 8192);
    };
    auto stB = [&](int slot, int kt, int uu) {
        g2lds16(gB + (size_t)uu * 64 * K + kt * 64, sB + slot * BSZ + uu * 8192);
    };

    // ---- fragment reads (swizzled address) ----
    // logical: row = base + lrow, byte col = p*64 + (l>>4)*16 ; phys col ^= (row&7)<<4,
    // row&7 == l&7 (all bases are multiples of 16)
    const int lrow = l & 15;
    const int c0 = ((l >> 4) << 4) ^ ((l & 7) << 4);
    const char* cAs = (const char*)As;
    const char* cBs = (const char*)Bs;
    auto rdA = [&](int slot, int qi, int ii, int p) {
        return (const bf16x8*)(cAs + slot * ASZ
            + (size_t)(qi * (BM / 2) + wm + ii * 16 + lrow) * 128 + (c0 ^ (p << 6)));
    };
    auto rdB = [&](int slot, int qj, int jj, int p) {
        return (const bf16x8*)(cBs + slot * BSZ
            + (size_t)(qj * 128 + wn + jj * 16 + lrow) * 128 + (c0 ^ (p << 6)));
    };

    f32x4 acc[FM][4];
#pragma unroll
    for (int i = 0; i < FM; ++i)
#pragma unroll
        for (int j = 0; j < 4; ++j)
#pragma unroll
            for (int r = 0; r < 4; ++r) acc[i][j][r] = 0.f;

    // ---- 4-phase tile body ----
    auto tile = [&](auto W0, auto W1, auto W2, int slot, int ktN, bool st) {
        const int ns = slot ^ 1;
        bf16x8 af[FMH][2], bf0[2][2], bf1[2][2];
        // phase 0: (qi=0,qj=0). stage next B-slice0.
        if (st) { stB(ns, ktN, 0); stB(ns, ktN, 1); }
        waitv<decltype(W0)::v>(); bar();
#pragma unroll
        for (int ii = 0; ii < FMH; ++ii)
#pragma unroll
            for (int p = 0; p < 2; ++p) af[ii][p] = *rdA(slot, 0, ii, p);
#pragma unroll
        for (int jj = 0; jj < 2; ++jj)
#pragma unroll
            for (int p = 0; p < 2; ++p) bf0[jj][p] = *rdB(slot, 0, jj, p);
        __builtin_amdgcn_s_setprio(1);
#pragma unroll
        for (int ii = 0; ii < FMH; ++ii)
#pragma unroll
            for (int jj = 0; jj < 2; ++jj)
#pragma unroll
                for (int p = 0; p < 2; ++p)
                    acc[ii][jj] = __builtin_amdgcn_mfma_f32_16x16x32_bf16(
                        bf0[jj][p], af[ii][p], acc[ii][jj], 0, 0, 0);
        __builtin_amdgcn_s_setprio(0);
        // phase 1: (qi=0,qj=1). stage next A-slice0.
        if (st) { stA(ns, ktN, 0); if constexpr (AUH == 2) stA(ns, ktN, 1); }
        waitv<decltype(W1)::v>(); bar();
#pragma unroll
        for (int jj = 0; jj < 2; ++jj)
#pragma unroll
            for (int p = 0; p < 2; ++p) bf1[jj][p] = *rdB(slot, 1, jj, p);
        __builtin_amdgcn_s_setprio(1);
#pragma unroll
        for (int ii = 0; ii < FMH; ++ii)
#pragma unroll
            for (int jj = 0; jj < 2; ++jj)
#pragma unroll
                for (int p = 0; p < 2; ++p)
                    acc[ii][2 + jj] = __builtin_amdgcn_mfma_f32_16x16x32_bf16(
                        bf1[jj][p], af[ii][p], acc[ii][2 + jj], 0, 0, 0);
        __builtin_amdgcn_s_setprio(0);
        // phase 2: (qi=1,qj=1). stage next B-slice1.
        if (st) { stB(ns, ktN, 2); stB(ns, ktN, 3); }
        waitv<decltype(W2)::v>(); bar();
#pragma unroll
        for (int ii = 0; ii < FMH; ++ii)
#pragma unroll
            for (int p = 0; p < 2; ++p) af[ii][p] = *rdA(slot, 1, ii, p);
        __builtin_amdgcn_s_setprio(1);
#pragma unroll
        for (int ii = 0; ii < FMH; ++ii)
#pragma unroll
            for (int jj = 0; jj < 2; ++jj)
#pragma unroll
                for (int p = 0; p < 2; ++p)
                    acc[FMH + ii][2 + jj] = __builtin_amdgcn_mfma_f32_16x16x32_bf16(
                        bf1[jj][p], af[ii][p], acc[FMH + ii][2 + jj], 0, 0, 0);
        __builtin_amdgcn_s_setprio(0);
        // phase 3: (qi=1,qj=0). stage next A-slice1. no wait/barrier (no fresh reads).
        if (st) { stA(ns, ktN, AUH); if constexpr (AUH == 2) stA(ns, ktN, 3); }
        __builtin_amdgcn_s_setprio(1);
#pragma unroll
        for (int ii = 0; ii < FMH; ++ii)
#pragma unroll
            for (int jj = 0; jj < 2; ++jj)
#pragma unroll
                for (int p = 0; p < 2; ++p)
                    acc[FMH + ii][jj] = __builtin_amdgcn_mfma_f32_16x16x32_bf16(
                        bf0[jj][p], af[ii][p], acc[FMH + ii][jj], 0, 0, 0);
        __builtin_amdgcn_s_setprio(0);
    };

    // prologue: stage tile 0 in issue order B0,A0,B1,A1 (FIFO invariant)
    stB(0, 0, 0); stB(0, 0, 1);
    stA(0, 0, 0); if constexpr (AUH == 2) stA(0, 0, 1);
    stB(0, 0, 2); stB(0, 0, 3);
    stA(0, 0, AUH); if constexpr (AUH == 2) stA(0, 0, 3);

    const int NT = K >> 6;
    for (int kt = 0; kt < NT - 1; ++kt) {
        if constexpr (BM == 256) tile(IC<6>{}, IC<6>{}, IC<6>{}, kt & 1, kt + 1, true);
        else                     tile(IC<5>{}, IC<4>{}, IC<5>{}, kt & 1, kt + 1, true);
    }
    if constexpr (BM == 256) tile(IC<4>{}, IC<2>{}, IC<0>{}, (NT - 1) & 1, 0, false);
    else                     tile(IC<3>{}, IC<1>{}, IC<0>{}, (NT - 1) & 1, 0, false);

    // ---- epilogue ----
    // m = rowA + wm + (i&(FMH-1))*16 + (i/FMH)*(BM/2) + (l&15)
    // n = colB + wn + (j&1)*16 + (j>>1)*128 + (l>>4)*4 + r
    const int m0 = rowA + wm + lrow;
    const int n0 = colB + wn + ((l >> 4) * 4);

    f32x4 gvv[4];
    if constexpr (MODE == MODE_STEP2) {
#pragma unroll
        for (int j = 0; j < 4; ++j)
            gvv[j] = *(const f32x4*)(g + n0 + (j & 1) * 16 + (j >> 1) * 128);
    }

#pragma unroll
    for (int i = 0; i < FM; ++i) {
        const int m = m0 + (i & (FMH - 1)) * 16 + (i / FMH) * (BM / 2);
#pragma unroll
        for (int j = 0; j < 4; ++j) {
            const size_t idx = (size_t)m * N + (n0 + (j & 1) * 16 + (j >> 1) * 128);
            const f32x4 c = acc[i][j];
            if constexpr (MODE == MODE_T) {
                bf16x4 o;
#pragma unroll
                for (int r = 0; r < 4; ++r) o[r] = (bf16_t)c[r];
                *(bf16x4*)(outH + idx) = o;
            } else if constexpr (MODE == MODE_B) {
                bf16x4 ob, ou, oa;
#pragma unroll
                for (int r = 0; r < 4; ++r) {
                    const float un = 0.1f * c[r];       // u1 = 0.1 b (u0=0 => a0=0)
                    ob[r] = (bf16_t)c[r];
                    ou[r] = (bf16_t)un;
                    oa[r] = (bf16_t)fmaxf(un - 0.1f, 0.f);
                }
                *(bf16x4*)(bb   + idx) = ob;
                *(bf16x4*)(u    + idx) = ou;
                *(bf16x4*)(outH + idx) = oa;
            } else if constexpr (MODE == MODE_STEP2) {
                const bf16x4 uv = *(const bf16x4*)(u  + idx);
                const bf16x4 bv = *(const bf16x4*)(bb + idx);
                bf16x4 ou, oa;
#pragma unroll
                for (int r = 0; r < 4; ++r) {
                    const float uo = (float)uv[r];
                    const float ao = fmaxf(uo - 0.1f, 0.f);    // a_old from u_old
                    const float un = 0.9f * uo + 0.1f * (float)bv[r]
                                   - 0.1f * c[r] + 0.1f * ao * gvv[j][r];
                    ou[r] = (bf16_t)un;
                    oa[r] = (bf16_t)fmaxf(un - 0.1f, 0.f);     // a_next (no race)
                }
                *(bf16x4*)(u    + idx) = ou;
                *(bf16x4*)(outH + idx) = oa;
            } else { // MODE_OUT
                *(f32x4*)(outF + idx) = c;
            }
        }
    }
}

__global__ void cast_x_kernel(const float* __restrict__ x, bf16_t* __restrict__ xh, int n) {
    int i = blockIdx.x * 256 + threadIdx.x;
    if (i < n) xh[i] = (bf16_t)x[i];
}

// Wh = bf16(W) [1024][4096] ; WT = bf16(W^T) [4096][1024]
__global__ void prep_w_kernel(const float* __restrict__ W,
                              bf16_t* __restrict__ Wh, bf16_t* __restrict__ WT) {
    int i = blockIdx.x * 256 + threadIdx.x;
    if (i < 1024 * 4096) {
        int k = i >> 12;
        int n = i & 4095;
        bf16_t v = (bf16_t)W[i];
        Wh[i] = v;
        WT[(size_t)n * 1024 + k] = v;
    }
}

// g[j] = sum_k W[k][j]^2
__global__ void prep_g_kernel(const float* __restrict__ W, float* __restrict__ g) {
    int j = blockIdx.x * 256 + threadIdx.x;
    if (j < 4096) {
        float s = 0.f;
        for (int k = 0; k < 1024; ++k) {
            float v = W[(size_t)k * 4096 + j];
            s += v * v;
        }
        g[j] = s;
    }
}

extern "C" void kernel_launch(void* const* d_in, const int* in_sizes, int n_in,
                              void* d_out, int out_size, void* d_ws, size_t ws_size,
                              hipStream_t stream)
{
    const float* x = (const float*)d_in[0];   // [8192][1024]
    const float* W = (const float*)d_in[1];   // [1024][4096]

    // d_out doubles as scratch until the final GEMM writes it:
    //   [0,16MiB): xh (bf16 x) until b-GEMM, then t ; [16MiB,+16KiB): g
    bf16_t* xh = (bf16_t*)d_out;
    bf16_t* tt = (bf16_t*)d_out;
    float*  gd = (float*)((char*)d_out + 16777216);

    char* ws = (char*)d_ws;                   // 208 MiB total (proven footprint)
    bf16_t* a  = (bf16_t*)(ws);               //  64 MiB [8192][4096]
    bf16_t* bb = (bf16_t*)(ws + 67108864);    //  64 MiB [8192][4096]
    bf16_t* u  = (bf16_t*)(ws + 134217728);   //  64 MiB [8192][4096]
    bf16_t* Wh = (bf16_t*)(ws + 201326592);   //   8 MiB [1024][4096]
    bf16_t* WT = (bf16_t*)(ws + 209715200);   //   8 MiB [4096][1024]

    cast_x_kernel<<<8388608 / 256, 256, 0, stream>>>(x, xh, 8388608);
    prep_w_kernel<<<4194304 / 256, 256, 0, stream>>>(W, Wh, WT);
    prep_g_kernel<<<16, 256, 0, stream>>>(W, gd);

    // b = x@W ; u1 = 0.1b ; a1 = relu(u1-0.1).  A=xh, Bt=WT, N=4096, K=1024
    gemm_bt<MODE_B, 256><<<dim3(16, 32), 512, 0, stream>>>(xh, WT, 4096, 1024,
                                                           nullptr, a, bb, u, nullptr);
    // 9 remaining steps: t = a@W^T (BM=128, N=1024) ; s = t@W fused update (BM=256)
    for (int s = 0; s < 9; ++s) {
        gemm_bt<MODE_T, 128><<<dim3(4, 64), 512, 0, stream>>>(a, Wh, 1024, 4096,
                                                              nullptr, tt, nullptr, nullptr, nullptr);
        gemm_bt<MODE_STEP2, 256><<<dim3(16, 32), 512, 0, stream>>>(tt, WT, 4096, 1024,
                                                                   nullptr, a, bb, u, gd);
    }
    // out = a@W^T : A=a, Bt=Wh, N=1024, K=4096, fp32 into d_out
    gemm_bt<MODE_OUT, 128><<<dim3(4, 64), 512, 0, stream>>>(a, Wh, 1024, 4096,
                                                            (float*)d_out, nullptr, nullptr, nullptr, nullptr);
}

// Round 3
// 2037.282 us; speedup vs baseline: 1.1081x; 1.0091x over previous
//
#include <hip/hip_runtime.h>
#include <hip/hip_bf16.h>

// LCA layer on MI355X — rank-factored steps, 4-phase counted-vmcnt GEMM core,
// NO materialized `a` (recomputed as relu(u-0.1) in T/OUT's reg-staged A path).
//   b = x@W ; g[j] = sum_k W[k][j]^2
//   u1 = 0.1 b
//   per step: t = relu(u-.1)@W^T ; s = t@W ; u' = 0.9u + 0.1b - 0.1s + 0.1*relu(u-.1)*g
//   out = relu(u-.1)@W^T (fp32)
//
// BM=256 (B/STEP2): round-2 proven core verbatim — ring-of-2 BK=64, 4 phases,
//   waits {6,6,6} main / {4,2,0} tail, 3 barriers/tile, slot-XOR swizzle
//   (zero SQ_LDS_BANK_CONFLICT measured). Epilogue writes only u (+bb in MODE_B).
// BM=128 (T/OUT): B-operand ring-of-2 via global_load_lds (4 granules/tile),
//   A-operand = relu(u) REG-STAGED into a single 16KB LDS buffer:
//   P0 issue 2 A-reg loads (tile k+1), P3 vmcnt(4) + relu + swizzled ds_write +
//   lgkmcnt(0). Mixed vmcnt FIFO (A-regs + B-gload_lds share the counter, order
//   pinned by per-phase asm fences): steady {P0:4, P1:4, P2:-, P3:4}, tail {2,0,-,skip}.
//   Barriers P0/P1/P3 (P2 reads only A written 4 barriers earlier).
// Operand swap retained: lane's 4 acc regs = 4 consecutive output cols at one row.
// Bijective XCD-chunk swizzle on block index (nwg % 8 == 0 for all grids).

typedef __bf16 bf16_t;
typedef __bf16 bf16x8 __attribute__((ext_vector_type(8)));
typedef __bf16 bf16x4 __attribute__((ext_vector_type(4)));
typedef float  f32x4  __attribute__((ext_vector_type(4)));

__device__ __forceinline__ void g2lds16(const void* g, void* l) {
    __builtin_amdgcn_global_load_lds(
        (const __attribute__((address_space(1))) void*)g,
        (__attribute__((address_space(3))) void*)l,
        16, 0, 0);
}

template<int N> __device__ __forceinline__ void waitv() {
    if constexpr (N == 0) asm volatile("s_waitcnt vmcnt(0)" ::: "memory");
    else if constexpr (N == 1) asm volatile("s_waitcnt vmcnt(1)" ::: "memory");
    else if constexpr (N == 2) asm volatile("s_waitcnt vmcnt(2)" ::: "memory");
    else if constexpr (N == 3) asm volatile("s_waitcnt vmcnt(3)" ::: "memory");
    else if constexpr (N == 4) asm volatile("s_waitcnt vmcnt(4)" ::: "memory");
    else if constexpr (N == 5) asm volatile("s_waitcnt vmcnt(5)" ::: "memory");
    else if constexpr (N == 6) asm volatile("s_waitcnt vmcnt(6)" ::: "memory");
}
__device__ __forceinline__ void bar() { __builtin_amdgcn_s_barrier(); }
__device__ __forceinline__ void waitlgkm0() {
    asm volatile("s_waitcnt lgkmcnt(0)" ::: "memory");
}

template<int n> struct IC { static constexpr int v = n; };

enum { MODE_B = 0, MODE_T = 1, MODE_STEP2 = 2, MODE_OUT = 3 };

// C[m][n] = sum_k A[m][k] * Bt[n][k]  (A:[M][K], Bt:[N][K], bf16, K%64==0).
// Grid: x covers N in 256-tiles, y covers M in BM-tiles. 512 threads.
template<int MODE, int BM>
__global__ __launch_bounds__(512, 2)
void gemm_bt(const bf16_t* __restrict__ A, const bf16_t* __restrict__ Bt,
             int N, int K,
             float*  __restrict__ outF,   // MODE_OUT: final fp32 output
             bf16_t* __restrict__ outH,   // MODE_T: t
             bf16_t* __restrict__ bb,     // MODE_B: write b ; MODE_STEP2: read b
             bf16_t* __restrict__ u,      // MODE_B: write u ; MODE_STEP2: rmw u
             const float* __restrict__ g) // MODE_STEP2: diag(W^T W), [N]
{
    constexpr int BN  = 256;
    constexpr int FM  = BM / 32;       // 8 (BM=256) or 4 (BM=128)
    constexpr int FMH = FM / 2;        // fragments per A-slice: 4 or 2
    constexpr int ASZ = BM * 128;      // bytes per A slot
    constexpr int BSZ = BN * 128;      // bytes per B slot

    __shared__ __attribute__((aligned(16))) bf16_t As[(BM == 256 ? 2 : 1) * BM * 64];
    __shared__ __attribute__((aligned(16))) bf16_t Bs[2 * BN * 64];

    const int t = threadIdx.x;
    const int l = t & 63;
    const int w = t >> 6;
    const int wm = (w >> 2) * (BM / 4);   // {0, BM/4}
    const int wn = (w & 3) * 32;          // {0,32,64,96}

    // bijective XCD-chunk swizzle (nwg % 8 == 0 for all our grids)
    const int gx  = gridDim.x;
    const int nwg = gx * gridDim.y;
    const int bid = blockIdx.y * gx + blockIdx.x;
    const int sw  = (bid & 7) * (nwg >> 3) + (bid >> 3);
    const int rowA = (sw / gx) * BM;
    const int colB = (sw % gx) * BN;

    // ---- B staging (linear LDS dest, inverse-swizzled global source) ----
    const int srow = t >> 3;
    const int scol = (((t & 7) ^ (srow & 7)) << 3);
    const bf16_t* gB = Bt + (size_t)(colB + srow) * K + scol;
    char* sB = (char*)Bs + t * 16;
    auto stB = [&](int slot, int kt, int uu) {
        g2lds16(gB + (size_t)uu * 64 * K + kt * 64, sB + slot * BSZ + uu * 8192);
    };

    // ---- fragment reads (swizzled address) ----
    const int lrow = l & 15;
    const int c0 = ((l >> 4) << 4) ^ ((l & 7) << 4);
    const char* cAs = (const char*)As;
    const char* cBs = (const char*)Bs;
    auto rdA = [&](int slot, int qi, int ii, int p) {
        return (const bf16x8*)(cAs + slot * ASZ
            + (size_t)(qi * (BM / 2) + wm + ii * 16 + lrow) * 128 + (c0 ^ (p << 6)));
    };
    auto rdB = [&](int slot, int qj, int jj, int p) {
        return (const bf16x8*)(cBs + slot * BSZ
            + (size_t)(qj * 128 + wn + jj * 16 + lrow) * 128 + (c0 ^ (p << 6)));
    };

    f32x4 acc[FM][4];
#pragma unroll
    for (int i = 0; i < FM; ++i)
#pragma unroll
        for (int j = 0; j < 4; ++j)
#pragma unroll
            for (int r = 0; r < 4; ++r) acc[i][j][r] = 0.f;

    const int NT = K >> 6;

    if constexpr (BM == 256) {
        // ---------------- round-2 proven core (verbatim) ----------------
        const bf16_t* gA = A + (size_t)(rowA + srow) * K + scol;
        char* sA = (char*)As + t * 16;
        auto stA = [&](int slot, int kt, int uu) {
            g2lds16(gA + (size_t)uu * 64 * K + kt * 64, sA + slot * ASZ + uu * 8192);
        };

        auto tile = [&](auto W0, auto W1, auto W2, int slot, int ktN, bool st) {
            const int ns = slot ^ 1;
            bf16x8 af[FMH][2], bf0[2][2], bf1[2][2];
            // phase 0: (qi=0,qj=0). stage next B-slice0.
            if (st) { stB(ns, ktN, 0); stB(ns, ktN, 1); }
            waitv<decltype(W0)::v>(); bar();
#pragma unroll
            for (int ii = 0; ii < FMH; ++ii)
#pragma unroll
                for (int p = 0; p < 2; ++p) af[ii][p] = *rdA(slot, 0, ii, p);
#pragma unroll
            for (int jj = 0; jj < 2; ++jj)
#pragma unroll
                for (int p = 0; p < 2; ++p) bf0[jj][p] = *rdB(slot, 0, jj, p);
            __builtin_amdgcn_s_setprio(1);
#pragma unroll
            for (int ii = 0; ii < FMH; ++ii)
#pragma unroll
                for (int jj = 0; jj < 2; ++jj)
#pragma unroll
                    for (int p = 0; p < 2; ++p)
                        acc[ii][jj] = __builtin_amdgcn_mfma_f32_16x16x32_bf16(
                            bf0[jj][p], af[ii][p], acc[ii][jj], 0, 0, 0);
            __builtin_amdgcn_s_setprio(0);
            // phase 1: (qi=0,qj=1). stage next A-slice0.
            if (st) { stA(ns, ktN, 0); stA(ns, ktN, 1); }
            waitv<decltype(W1)::v>(); bar();
#pragma unroll
            for (int jj = 0; jj < 2; ++jj)
#pragma unroll
                for (int p = 0; p < 2; ++p) bf1[jj][p] = *rdB(slot, 1, jj, p);
            __builtin_amdgcn_s_setprio(1);
#pragma unroll
            for (int ii = 0; ii < FMH; ++ii)
#pragma unroll
                for (int jj = 0; jj < 2; ++jj)
#pragma unroll
                    for (int p = 0; p < 2; ++p)
                        acc[ii][2 + jj] = __builtin_amdgcn_mfma_f32_16x16x32_bf16(
                            bf1[jj][p], af[ii][p], acc[ii][2 + jj], 0, 0, 0);
            __builtin_amdgcn_s_setprio(0);
            // phase 2: (qi=1,qj=1). stage next B-slice1.
            if (st) { stB(ns, ktN, 2); stB(ns, ktN, 3); }
            waitv<decltype(W2)::v>(); bar();
#pragma unroll
            for (int ii = 0; ii < FMH; ++ii)
#pragma unroll
                for (int p = 0; p < 2; ++p) af[ii][p] = *rdA(slot, 1, ii, p);
            __builtin_amdgcn_s_setprio(1);
#pragma unroll
            for (int ii = 0; ii < FMH; ++ii)
#pragma unroll
                for (int jj = 0; jj < 2; ++jj)
#pragma unroll
                    for (int p = 0; p < 2; ++p)
                        acc[FMH + ii][2 + jj] = __builtin_amdgcn_mfma_f32_16x16x32_bf16(
                            bf1[jj][p], af[ii][p], acc[FMH + ii][2 + jj], 0, 0, 0);
            __builtin_amdgcn_s_setprio(0);
            // phase 3: (qi=1,qj=0). stage next A-slice1. no wait/barrier.
            if (st) { stA(ns, ktN, 2); stA(ns, ktN, 3); }
            __builtin_amdgcn_s_setprio(1);
#pragma unroll
            for (int ii = 0; ii < FMH; ++ii)
#pragma unroll
                for (int jj = 0; jj < 2; ++jj)
#pragma unroll
                    for (int p = 0; p < 2; ++p)
                        acc[FMH + ii][jj] = __builtin_amdgcn_mfma_f32_16x16x32_bf16(
                            bf0[jj][p], af[ii][p], acc[FMH + ii][jj], 0, 0, 0);
            __builtin_amdgcn_s_setprio(0);
        };

        // prologue: stage tile 0 in issue order B0,A0,B1,A1 (FIFO invariant)
        stB(0, 0, 0); stB(0, 0, 1);
        stA(0, 0, 0); stA(0, 0, 1);
        stB(0, 0, 2); stB(0, 0, 3);
        stA(0, 0, 2); stA(0, 0, 3);

        for (int kt = 0; kt < NT - 1; ++kt)
            tile(IC<6>{}, IC<6>{}, IC<6>{}, kt & 1, kt + 1, true);
        tile(IC<4>{}, IC<2>{}, IC<0>{}, (NT - 1) & 1, 0, false);
    } else {
        // ------------- BM=128: reg-staged A = relu(u - 0.1) --------------
        // thread t: A granule g -> row g*64 + (t>>3), col elems (t&7)*8 (natural)
        const int s_arow = t >> 3;
        const int s_acb  = ((t & 7) << 4) ^ ((s_arow & 7) << 4);  // swizzled byte col
        const bf16_t* gAr = A + (size_t)(rowA + s_arow) * K + (t & 7) * 8;
        auto reluv = [&](bf16x8 v) {
            bf16x8 r;
#pragma unroll
            for (int e = 0; e < 8; ++e)
                r[e] = (bf16_t)fmaxf((float)v[e] - 0.1f, 0.f);
            return r;
        };
        auto wrA = [&](bf16x8 v, int gg) {
            *(bf16x8*)((char*)As + (size_t)(gg * 64 + s_arow) * 128 + s_acb) = v;
        };

        // prologue: A(0) regs -> drain -> LDS ; then B(0) x4  => FIFO = [B0 x4]
        {
            bf16x8 a0 = *(const bf16x8*)(gAr);
            bf16x8 a1 = *(const bf16x8*)(gAr + (size_t)64 * K);
            waitv<0>();
            wrA(reluv(a0), 0);
            wrA(reluv(a1), 1);
            waitlgkm0();
            stB(0, 0, 0); stB(0, 0, 1); stB(0, 0, 2); stB(0, 0, 3);
        }

        for (int kt = 0; kt < NT; ++kt) {
            const bool st = (kt + 1 < NT);
            const int slot = kt & 1, ns = slot ^ 1;
            bf16x8 af[FMH][2], bf0[2][2], bf1[2][2];
            bf16x8 nA0, nA1;
            // P0: issue next A regs; read A-q0 + B-q0; MFMA quad (0,0)
            if (st) {
                nA0 = *(const bf16x8*)(gAr + (kt + 1) * 64);
                nA1 = *(const bf16x8*)(gAr + (size_t)64 * K + (kt + 1) * 64);
            }
            if (st) waitv<4>(); else waitv<2>();
            bar();
#pragma unroll
            for (int ii = 0; ii < FMH; ++ii)
#pragma unroll
                for (int p = 0; p < 2; ++p) af[ii][p] = *rdA(0, 0, ii, p);
#pragma unroll
            for (int jj = 0; jj < 2; ++jj)
#pragma unroll
                for (int p = 0; p < 2; ++p) bf0[jj][p] = *rdB(slot, 0, jj, p);
            __builtin_amdgcn_s_setprio(1);
#pragma unroll
            for (int ii = 0; ii < FMH; ++ii)
#pragma unroll
                for (int jj = 0; jj < 2; ++jj)
#pragma unroll
                    for (int p = 0; p < 2; ++p)
                        acc[ii][jj] = __builtin_amdgcn_mfma_f32_16x16x32_bf16(
                            bf0[jj][p], af[ii][p], acc[ii][jj], 0, 0, 0);
            __builtin_amdgcn_s_setprio(0);
            // P1: stage B-g01(next); read B-q1; MFMA quad (0,1)
            if (st) { stB(ns, kt + 1, 0); stB(ns, kt + 1, 1); }
            if (st) waitv<4>(); else waitv<0>();
            bar();
#pragma unroll
            for (int jj = 0; jj < 2; ++jj)
#pragma unroll
                for (int p = 0; p < 2; ++p) bf1[jj][p] = *rdB(slot, 1, jj, p);
            __builtin_amdgcn_s_setprio(1);
#pragma unroll
            for (int ii = 0; ii < FMH; ++ii)
#pragma unroll
                for (int jj = 0; jj < 2; ++jj)
#pragma unroll
                    for (int p = 0; p < 2; ++p)
                        acc[ii][2 + jj] = __builtin_amdgcn_mfma_f32_16x16x32_bf16(
                            bf1[jj][p], af[ii][p], acc[ii][2 + jj], 0, 0, 0);
            __builtin_amdgcn_s_setprio(0);
            // P2: stage B-g23(next); read A-q1 (written 4 barriers ago); MFMA (1,1)
            if (st) { stB(ns, kt + 1, 2); stB(ns, kt + 1, 3); }
#pragma unroll
            for (int ii = 0; ii < FMH; ++ii)
#pragma unroll
                for (int p = 0; p < 2; ++p) af[ii][p] = *rdA(0, 1, ii, p);
            __builtin_amdgcn_s_setprio(1);
#pragma unroll
            for (int ii = 0; ii < FMH; ++ii)
#pragma unroll
                for (int jj = 0; jj < 2; ++jj)
#pragma unroll
                    for (int p = 0; p < 2; ++p)
                        acc[FMH + ii][2 + jj] = __builtin_amdgcn_mfma_f32_16x16x32_bf16(
                            bf1[jj][p], af[ii][p], acc[FMH + ii][2 + jj], 0, 0, 0);
            __builtin_amdgcn_s_setprio(0);
            // P3: barrier (protects A overwrite vs P2 readers); write next A; MFMA (1,0)
            bar();
            if (st) {
                waitv<4>();
                wrA(reluv(nA0), 0);
                wrA(reluv(nA1), 1);
                waitlgkm0();
            }
            __builtin_amdgcn_s_setprio(1);
#pragma unroll
            for (int ii = 0; ii < FMH; ++ii)
#pragma unroll
                for (int jj = 0; jj < 2; ++jj)
#pragma unroll
                    for (int p = 0; p < 2; ++p)
                        acc[FMH + ii][jj] = __builtin_amdgcn_mfma_f32_16x16x32_bf16(
                            bf0[jj][p], af[ii][p], acc[FMH + ii][jj], 0, 0, 0);
            __builtin_amdgcn_s_setprio(0);
        }
    }

    // ---- epilogue ----
    // m = rowA + wm + (i&(FMH-1))*16 + (i/FMH)*(BM/2) + (l&15)
    // n = colB + wn + (j&1)*16 + (j>>1)*128 + (l>>4)*4 + r
    const int m0 = rowA + wm + lrow;
    const int n0 = colB + wn + ((l >> 4) * 4);

    f32x4 gvv[4];
    if constexpr (MODE == MODE_STEP2) {
#pragma unroll
        for (int j = 0; j < 4; ++j)
            gvv[j] = *(const f32x4*)(g + n0 + (j & 1) * 16 + (j >> 1) * 128);
    }

#pragma unroll
    for (int i = 0; i < FM; ++i) {
        const int m = m0 + (i & (FMH - 1)) * 16 + (i / FMH) * (BM / 2);
#pragma unroll
        for (int j = 0; j < 4; ++j) {
            const size_t idx = (size_t)m * N + (n0 + (j & 1) * 16 + (j >> 1) * 128);
            const f32x4 c = acc[i][j];
            if constexpr (MODE == MODE_T) {
                bf16x4 o;
#pragma unroll
                for (int r = 0; r < 4; ++r) o[r] = (bf16_t)c[r];
                *(bf16x4*)(outH + idx) = o;
            } else if constexpr (MODE == MODE_B) {
                bf16x4 ob, ou;
#pragma unroll
                for (int r = 0; r < 4; ++r) {
                    const float un = 0.1f * c[r];       // u1 = 0.1 b (u0=0 => a0=0)
                    ob[r] = (bf16_t)c[r];
                    ou[r] = (bf16_t)un;
                }
                *(bf16x4*)(bb + idx) = ob;
                *(bf16x4*)(u  + idx) = ou;
            } else if constexpr (MODE == MODE_STEP2) {
                const bf16x4 uv = *(const bf16x4*)(u  + idx);
                const bf16x4 bv = *(const bf16x4*)(bb + idx);
                bf16x4 ou;
#pragma unroll
                for (int r = 0; r < 4; ++r) {
                    const float uo = (float)uv[r];
                    const float ao = fmaxf(uo - 0.1f, 0.f);    // a_old from u_old
                    const float un = 0.9f * uo + 0.1f * (float)bv[r]
                                   - 0.1f * c[r] + 0.1f * ao * gvv[j][r];
                    ou[r] = (bf16_t)un;
                }
                *(bf16x4*)(u + idx) = ou;
            } else { // MODE_OUT
                *(f32x4*)(outF + idx) = c;
            }
        }
    }
}

__global__ void cast_x_kernel(const float* __restrict__ x, bf16_t* __restrict__ xh, int n) {
    int i = blockIdx.x * 256 + threadIdx.x;
    if (i < n) xh[i] = (bf16_t)x[i];
}

// Wh = bf16(W) [1024][4096] ; WT = bf16(W^T) [4096][1024]
__global__ void prep_w_kernel(const float* __restrict__ W,
                              bf16_t* __restrict__ Wh, bf16_t* __restrict__ WT) {
    int i = blockIdx.x * 256 + threadIdx.x;
    if (i < 1024 * 4096) {
        int k = i >> 12;
        int n = i & 4095;
        bf16_t v = (bf16_t)W[i];
        Wh[i] = v;
        WT[(size_t)n * 1024 + k] = v;
    }
}

// g[j] = sum_k W[k][j]^2
__global__ void prep_g_kernel(const float* __restrict__ W, float* __restrict__ g) {
    int j = blockIdx.x * 256 + threadIdx.x;
    if (j < 4096) {
        float s = 0.f;
        for (int k = 0; k < 1024; ++k) {
            float v = W[(size_t)k * 4096 + j];
            s += v * v;
        }
        g[j] = s;
    }
}

extern "C" void kernel_launch(void* const* d_in, const int* in_sizes, int n_in,
                              void* d_out, int out_size, void* d_ws, size_t ws_size,
                              hipStream_t stream)
{
    const float* x = (const float*)d_in[0];   // [8192][1024]
    const float* W = (const float*)d_in[1];   // [1024][4096]

    // d_out doubles as scratch until the final GEMM writes it:
    //   [0,16MiB): xh (bf16 x) until b-GEMM, then t ; [16MiB,+16KiB): g
    bf16_t* xh = (bf16_t*)d_out;
    bf16_t* tt = (bf16_t*)d_out;
    float*  gd = (float*)((char*)d_out + 16777216);

    char* ws = (char*)d_ws;                   // (a-slot now unused; layout kept)
    bf16_t* bb = (bf16_t*)(ws + 67108864);    //  64 MiB [8192][4096]
    bf16_t* u  = (bf16_t*)(ws + 134217728);   //  64 MiB [8192][4096]
    bf16_t* Wh = (bf16_t*)(ws + 201326592);   //   8 MiB [1024][4096]
    bf16_t* WT = (bf16_t*)(ws + 209715200);   //   8 MiB [4096][1024]

    cast_x_kernel<<<8388608 / 256, 256, 0, stream>>>(x, xh, 8388608);
    prep_w_kernel<<<4194304 / 256, 256, 0, stream>>>(W, Wh, WT);
    prep_g_kernel<<<16, 256, 0, stream>>>(W, gd);

    // b = x@W ; u1 = 0.1b.  A=xh, Bt=WT, N=4096, K=1024
    gemm_bt<MODE_B, 256><<<dim3(16, 32), 512, 0, stream>>>(xh, WT, 4096, 1024,
                                                           nullptr, nullptr, bb, u, nullptr);
    // 9 remaining steps: t = relu(u)@W^T (BM=128, A=u) ; s = t@W fused update (BM=256)
    for (int s = 0; s < 9; ++s) {
        gemm_bt<MODE_T, 128><<<dim3(4, 64), 512, 0, stream>>>(u, Wh, 1024, 4096,
                                                              nullptr, tt, nullptr, nullptr, nullptr);
        gemm_bt<MODE_STEP2, 256><<<dim3(16, 32), 512, 0, stream>>>(tt, WT, 4096, 1024,
                                                                   nullptr, nullptr, bb, u, gd);
    }
    // out = relu(u)@W^T : A=u, Bt=Wh, N=1024, K=4096, fp32 into d_out
    gemm_bt<MODE_OUT, 128><<<dim3(4, 64), 512, 0, stream>>>(u, Wh, 1024, 4096,
                                                            (float*)d_out, nullptr, nullptr, nullptr, nullptr);
}

// Round 4
// 1774.703 us; speedup vs baseline: 1.2720x; 1.1480x over previous
//
#include <hip/hip_runtime.h>
#include <hip/hip_bf16.h>

// LCA layer on MI355X — rank-factored steps, 4-phase counted-vmcnt GEMM cores,
// no materialized `a` (relu(u-0.1) recomputed in T/OUT's reg-bounced A path).
//   b = x@W ; g[j] = sum_k W[k][j]^2
//   u1 = 0.1 b
//   per step: t = relu(u-.1)@W^T ; s = t@W ; u' = 0.9u + 0.1b - 0.1s + 0.1*relu(u-.1)*g
//   out = relu(u-.1)@W^T (fp32)
//
// BM=256 (B/STEP2): round-2/3 proven core VERBATIM — ring-of-2 BK=64, 4 phases,
//   waits {6,6,6} main / {4,2,0} tail, slot-XOR swizzle (0 bank conflicts measured).
// BM=128 (T/OUT), NEW this round: A = relu(u) reg-bounced into a DOUBLE-buffered
//   As ring (2x16KB). A-regs for tile k+2 issued at tile k P0 (7-phase flight vs
//   round-3's 3); relu+ds_write into slot ns at P2 (overlapped with MFMA);
//   lgkmcnt(0) at P3 (write-visibility before next tile's P0 barrier).
//   Mixed vmcnt FIFO (A-regs + B-gload_lds in issue order A(k+2) | B01 | B23):
//   steady {P0:4, P1:4}, tail kt=NT-2 {2,2}, kt=NT-1 {2,0}. 2 barriers/tile.
// Operand swap retained: lane's 4 acc regs = 4 consecutive output cols at one row.
// Bijective XCD-chunk swizzle on block index (nwg % 8 == 0 for all grids).
// Prep kernels rebuilt: parallel g-reduction (128 blocks + atomicAdd), LDS-tiled
// W transpose (64x128 tiles, [64][130] pad), float4 cast.

typedef __bf16 bf16_t;
typedef __bf16 bf16x8 __attribute__((ext_vector_type(8)));
typedef __bf16 bf16x4 __attribute__((ext_vector_type(4)));
typedef float  f32x4  __attribute__((ext_vector_type(4)));

__device__ __forceinline__ void g2lds16(const void* g, void* l) {
    __builtin_amdgcn_global_load_lds(
        (const __attribute__((address_space(1))) void*)g,
        (__attribute__((address_space(3))) void*)l,
        16, 0, 0);
}

template<int N> __device__ __forceinline__ void waitv() {
    if constexpr (N == 0) asm volatile("s_waitcnt vmcnt(0)" ::: "memory");
    else if constexpr (N == 1) asm volatile("s_waitcnt vmcnt(1)" ::: "memory");
    else if constexpr (N == 2) asm volatile("s_waitcnt vmcnt(2)" ::: "memory");
    else if constexpr (N == 3) asm volatile("s_waitcnt vmcnt(3)" ::: "memory");
    else if constexpr (N == 4) asm volatile("s_waitcnt vmcnt(4)" ::: "memory");
    else if constexpr (N == 5) asm volatile("s_waitcnt vmcnt(5)" ::: "memory");
    else if constexpr (N == 6) asm volatile("s_waitcnt vmcnt(6)" ::: "memory");
}
__device__ __forceinline__ void bar() { __builtin_amdgcn_s_barrier(); }
__device__ __forceinline__ void waitlgkm0() {
    asm volatile("s_waitcnt lgkmcnt(0)" ::: "memory");
}
__device__ __forceinline__ void fence() { asm volatile("" ::: "memory"); }

template<int n> struct IC { static constexpr int v = n; };

enum { MODE_B = 0, MODE_T = 1, MODE_STEP2 = 2, MODE_OUT = 3 };

// C[m][n] = sum_k A[m][k] * Bt[n][k]  (A:[M][K], Bt:[N][K], bf16, K%64==0).
// Grid: x covers N in 256-tiles, y covers M in BM-tiles. 512 threads.
template<int MODE, int BM>
__global__ __launch_bounds__(512, 2)
void gemm_bt(const bf16_t* __restrict__ A, const bf16_t* __restrict__ Bt,
             int N, int K,
             float*  __restrict__ outF,   // MODE_OUT: final fp32 output
             bf16_t* __restrict__ outH,   // MODE_T: t
             bf16_t* __restrict__ bb,     // MODE_B: write b ; MODE_STEP2: read b
             bf16_t* __restrict__ u,      // MODE_B: write u ; MODE_STEP2: rmw u
             const float* __restrict__ g) // MODE_STEP2: diag(W^T W), [N]
{
    constexpr int BN  = 256;
    constexpr int FM  = BM / 32;       // 8 (BM=256) or 4 (BM=128)
    constexpr int FMH = FM / 2;        // fragments per A-slice: 4 or 2
    constexpr int ASZ = BM * 128;      // bytes per A slot
    constexpr int BSZ = BN * 128;      // bytes per B slot

    __shared__ __attribute__((aligned(16))) bf16_t As[2 * BM * 64];
    __shared__ __attribute__((aligned(16))) bf16_t Bs[2 * BN * 64];

    const int t = threadIdx.x;
    const int l = t & 63;
    const int w = t >> 6;
    const int wm = (w >> 2) * (BM / 4);   // {0, BM/4}
    const int wn = (w & 3) * 32;          // {0,32,64,96}

    // bijective XCD-chunk swizzle (nwg % 8 == 0 for all our grids)
    const int gx  = gridDim.x;
    const int nwg = gx * gridDim.y;
    const int bid = blockIdx.y * gx + blockIdx.x;
    const int sw  = (bid & 7) * (nwg >> 3) + (bid >> 3);
    const int rowA = (sw / gx) * BM;
    const int colB = (sw % gx) * BN;

    // ---- B staging (linear LDS dest, inverse-swizzled global source) ----
    const int srow = t >> 3;
    const int scol = (((t & 7) ^ (srow & 7)) << 3);
    const bf16_t* gB = Bt + (size_t)(colB + srow) * K + scol;
    char* sB = (char*)Bs + t * 16;
    auto stB = [&](int slot, int kt, int uu) {
        g2lds16(gB + (size_t)uu * 64 * K + kt * 64, sB + slot * BSZ + uu * 8192);
    };

    // ---- fragment reads (swizzled address) ----
    const int lrow = l & 15;
    const int c0 = ((l >> 4) << 4) ^ ((l & 7) << 4);
    const char* cAs = (const char*)As;
    const char* cBs = (const char*)Bs;
    auto rdA = [&](int slot, int qi, int ii, int p) {
        return (const bf16x8*)(cAs + slot * ASZ
            + (size_t)(qi * (BM / 2) + wm + ii * 16 + lrow) * 128 + (c0 ^ (p << 6)));
    };
    auto rdB = [&](int slot, int qj, int jj, int p) {
        return (const bf16x8*)(cBs + slot * BSZ
            + (size_t)(qj * 128 + wn + jj * 16 + lrow) * 128 + (c0 ^ (p << 6)));
    };

    f32x4 acc[FM][4];
#pragma unroll
    for (int i = 0; i < FM; ++i)
#pragma unroll
        for (int j = 0; j < 4; ++j)
#pragma unroll
            for (int r = 0; r < 4; ++r) acc[i][j][r] = 0.f;

    const int NT = K >> 6;

    if constexpr (BM == 256) {
        // ---------------- round-2/3 proven core (verbatim) ----------------
        const bf16_t* gA = A + (size_t)(rowA + srow) * K + scol;
        char* sA = (char*)As + t * 16;
        auto stA = [&](int slot, int kt, int uu) {
            g2lds16(gA + (size_t)uu * 64 * K + kt * 64, sA + slot * ASZ + uu * 8192);
        };

        auto tile = [&](auto W0, auto W1, auto W2, int slot, int ktN, bool st) {
            const int ns = slot ^ 1;
            bf16x8 af[FMH][2], bf0[2][2], bf1[2][2];
            // phase 0: (qi=0,qj=0). stage next B-slice0.
            if (st) { stB(ns, ktN, 0); stB(ns, ktN, 1); }
            waitv<decltype(W0)::v>(); bar();
#pragma unroll
            for (int ii = 0; ii < FMH; ++ii)
#pragma unroll
                for (int p = 0; p < 2; ++p) af[ii][p] = *rdA(slot, 0, ii, p);
#pragma unroll
            for (int jj = 0; jj < 2; ++jj)
#pragma unroll
                for (int p = 0; p < 2; ++p) bf0[jj][p] = *rdB(slot, 0, jj, p);
            __builtin_amdgcn_s_setprio(1);
#pragma unroll
            for (int ii = 0; ii < FMH; ++ii)
#pragma unroll
                for (int jj = 0; jj < 2; ++jj)
#pragma unroll
                    for (int p = 0; p < 2; ++p)
                        acc[ii][jj] = __builtin_amdgcn_mfma_f32_16x16x32_bf16(
                            bf0[jj][p], af[ii][p], acc[ii][jj], 0, 0, 0);
            __builtin_amdgcn_s_setprio(0);
            // phase 1: (qi=0,qj=1). stage next A-slice0.
            if (st) { stA(ns, ktN, 0); stA(ns, ktN, 1); }
            waitv<decltype(W1)::v>(); bar();
#pragma unroll
            for (int jj = 0; jj < 2; ++jj)
#pragma unroll
                for (int p = 0; p < 2; ++p) bf1[jj][p] = *rdB(slot, 1, jj, p);
            __builtin_amdgcn_s_setprio(1);
#pragma unroll
            for (int ii = 0; ii < FMH; ++ii)
#pragma unroll
                for (int jj = 0; jj < 2; ++jj)
#pragma unroll
                    for (int p = 0; p < 2; ++p)
                        acc[ii][2 + jj] = __builtin_amdgcn_mfma_f32_16x16x32_bf16(
                            bf1[jj][p], af[ii][p], acc[ii][2 + jj], 0, 0, 0);
            __builtin_amdgcn_s_setprio(0);
            // phase 2: (qi=1,qj=1). stage next B-slice1.
            if (st) { stB(ns, ktN, 2); stB(ns, ktN, 3); }
            waitv<decltype(W2)::v>(); bar();
#pragma unroll
            for (int ii = 0; ii < FMH; ++ii)
#pragma unroll
                for (int p = 0; p < 2; ++p) af[ii][p] = *rdA(slot, 1, ii, p);
            __builtin_amdgcn_s_setprio(1);
#pragma unroll
            for (int ii = 0; ii < FMH; ++ii)
#pragma unroll
                for (int jj = 0; jj < 2; ++jj)
#pragma unroll
                    for (int p = 0; p < 2; ++p)
                        acc[FMH + ii][2 + jj] = __builtin_amdgcn_mfma_f32_16x16x32_bf16(
                            bf1[jj][p], af[ii][p], acc[FMH + ii][2 + jj], 0, 0, 0);
            __builtin_amdgcn_s_setprio(0);
            // phase 3: (qi=1,qj=0). stage next A-slice1. no wait/barrier.
            if (st) { stA(ns, ktN, 2); stA(ns, ktN, 3); }
            __builtin_amdgcn_s_setprio(1);
#pragma unroll
            for (int ii = 0; ii < FMH; ++ii)
#pragma unroll
                for (int jj = 0; jj < 2; ++jj)
#pragma unroll
                    for (int p = 0; p < 2; ++p)
                        acc[FMH + ii][jj] = __builtin_amdgcn_mfma_f32_16x16x32_bf16(
                            bf0[jj][p], af[ii][p], acc[FMH + ii][jj], 0, 0, 0);
            __builtin_amdgcn_s_setprio(0);
        };

        // prologue: stage tile 0 in issue order B0,A0,B1,A1 (FIFO invariant)
        stB(0, 0, 0); stB(0, 0, 1);
        stA(0, 0, 0); stA(0, 0, 1);
        stB(0, 0, 2); stB(0, 0, 3);
        stA(0, 0, 2); stA(0, 0, 3);

        for (int kt = 0; kt < NT - 1; ++kt)
            tile(IC<6>{}, IC<6>{}, IC<6>{}, kt & 1, kt + 1, true);
        tile(IC<4>{}, IC<2>{}, IC<0>{}, (NT - 1) & 1, 0, false);
    } else {
        // ------- BM=128: A = relu(u - 0.1), reg-bounced, DOUBLE-buffered -------
        // thread t: A granule g -> row g*64 + (t>>3), col elems (t&7)*8 (natural)
        const int s_arow = t >> 3;
        const int s_acb  = ((t & 7) << 4) ^ ((s_arow & 7) << 4);  // swizzled byte col
        const bf16_t* gAr = A + (size_t)(rowA + s_arow) * K + (t & 7) * 8;
        auto reluv = [&](bf16x8 v) {
            bf16x8 r;
#pragma unroll
            for (int e = 0; e < 8; ++e)
                r[e] = (bf16_t)fmaxf((float)v[e] - 0.1f, 0.f);
            return r;
        };
        auto wrA = [&](bf16x8 v, int gg, int slot) {
            *(bf16x8*)((char*)As + slot * ASZ
                       + (size_t)(gg * 64 + s_arow) * 128 + s_acb) = v;
        };

        bf16x8 curA0, curA1;   // regs holding A(kt+1), written to LDS at tile kt P2
        // prologue: A(0) regs -> drain -> LDS slot0 ; issue A(1) ; stage B(0)x4
        {
            bf16x8 p0 = *(const bf16x8*)(gAr);
            bf16x8 p1 = *(const bf16x8*)(gAr + (size_t)64 * K);
            waitv<0>();
            wrA(reluv(p0), 0, 0);
            wrA(reluv(p1), 1, 0);
            waitlgkm0();
            curA0 = *(const bf16x8*)(gAr + 64);
            curA1 = *(const bf16x8*)(gAr + (size_t)64 * K + 64);
            fence();
            stB(0, 0, 0); stB(0, 0, 1); stB(0, 0, 2); stB(0, 0, 3);
        }
        // steady FIFO entering tile kt P0: [A(kt+1)2, B(kt)4] (6 outstanding)

        for (int kt = 0; kt < NT; ++kt) {
            const int slot = kt & 1, ns = slot ^ 1;
            const bool iA = (kt + 2 < NT);   // issue A-regs for tile kt+2
            const bool sB = (kt + 1 < NT);   // stage B(kt+1), write A(kt+1)
            bf16x8 af[FMH][2], bf0[2][2], bf1[2][2];
            bf16x8 nA0, nA1;
            // P0: issue A(kt+2) regs; drain A(kt+1)+B(kt)01; read A q0 + B q0; MFMA (0,0)q
            if (iA) {
                nA0 = *(const bf16x8*)(gAr + (kt + 2) * 64);
                nA1 = *(const bf16x8*)(gAr + (size_t)64 * K + (kt + 2) * 64);
            }
            if (kt < NT - 2) waitv<4>(); else waitv<2>();
            bar();
#pragma unroll
            for (int ii = 0; ii < FMH; ++ii)
#pragma unroll
                for (int p = 0; p < 2; ++p) af[ii][p] = *rdA(slot, 0, ii, p);
#pragma unroll
            for (int jj = 0; jj < 2; ++jj)
#pragma unroll
                for (int p = 0; p < 2; ++p) bf0[jj][p] = *rdB(slot, 0, jj, p);
            __builtin_amdgcn_s_setprio(1);
#pragma unroll
            for (int ii = 0; ii < FMH; ++ii)
#pragma unroll
                for (int jj = 0; jj < 2; ++jj)
#pragma unroll
                    for (int p = 0; p < 2; ++p)
                        acc[ii][jj] = __builtin_amdgcn_mfma_f32_16x16x32_bf16(
                            bf0[jj][p], af[ii][p], acc[ii][jj], 0, 0, 0);
            __builtin_amdgcn_s_setprio(0);
            // P1: stage B(kt+1)01; drain B(kt)23; read B q1; MFMA (0,1)q
            if (sB) { stB(ns, kt + 1, 0); stB(ns, kt + 1, 1); }
            if (kt < NT - 2) waitv<4>();
            else if (kt == NT - 2) waitv<2>();
            else waitv<0>();
            bar();
#pragma unroll
            for (int jj = 0; jj < 2; ++jj)
#pragma unroll
                for (int p = 0; p < 2; ++p) bf1[jj][p] = *rdB(slot, 1, jj, p);
            __builtin_amdgcn_s_setprio(1);
#pragma unroll
            for (int ii = 0; ii < FMH; ++ii)
#pragma unroll
                for (int jj = 0; jj < 2; ++jj)
#pragma unroll
                    for (int p = 0; p < 2; ++p)
                        acc[ii][2 + jj] = __builtin_amdgcn_mfma_f32_16x16x32_bf16(
                            bf1[jj][p], af[ii][p], acc[ii][2 + jj], 0, 0, 0);
            __builtin_amdgcn_s_setprio(0);
            // P2: stage B(kt+1)23; read A q1; relu+write A(kt+1) into slot ns; MFMA (1,1)q
            if (sB) { stB(ns, kt + 1, 2); stB(ns, kt + 1, 3); }
#pragma unroll
            for (int ii = 0; ii < FMH; ++ii)
#pragma unroll
                for (int p = 0; p < 2; ++p) af[ii][p] = *rdA(slot, 1, ii, p);
            if (sB) {
                wrA(reluv(curA0), 0, ns);
                wrA(reluv(curA1), 1, ns);
            }
            __builtin_amdgcn_s_setprio(1);
#pragma unroll
            for (int ii = 0; ii < FMH; ++ii)
#pragma unroll
                for (int jj = 0; jj < 2; ++jj)
#pragma unroll
                    for (int p = 0; p < 2; ++p)
                        acc[FMH + ii][2 + jj] = __builtin_amdgcn_mfma_f32_16x16x32_bf16(
                            bf1[jj][p], af[ii][p], acc[FMH + ii][2 + jj], 0, 0, 0);
            __builtin_amdgcn_s_setprio(0);
            // P3: drain ds_writes (visibility before next P0 bar); MFMA (1,0)q; rotate
            waitlgkm0();
            __builtin_amdgcn_s_setprio(1);
#pragma unroll
            for (int ii = 0; ii < FMH; ++ii)
#pragma unroll
                for (int jj = 0; jj < 2; ++jj)
#pragma unroll
                    for (int p = 0; p < 2; ++p)
                        acc[FMH + ii][jj] = __builtin_amdgcn_mfma_f32_16x16x32_bf16(
                            bf0[jj][p], af[ii][p], acc[FMH + ii][jj], 0, 0, 0);
            __builtin_amdgcn_s_setprio(0);
            if (iA) { curA0 = nA0; curA1 = nA1; }
        }
    }

    // ---- epilogue ----
    // m = rowA + wm + (i&(FMH-1))*16 + (i/FMH)*(BM/2) + (l&15)
    // n = colB + wn + (j&1)*16 + (j>>1)*128 + (l>>4)*4 + r
    const int m0 = rowA + wm + lrow;
    const int n0 = colB + wn + ((l >> 4) * 4);

    f32x4 gvv[4];
    if constexpr (MODE == MODE_STEP2) {
#pragma unroll
        for (int j = 0; j < 4; ++j)
            gvv[j] = *(const f32x4*)(g + n0 + (j & 1) * 16 + (j >> 1) * 128);
    }

#pragma unroll
    for (int i = 0; i < FM; ++i) {
        const int m = m0 + (i & (FMH - 1)) * 16 + (i / FMH) * (BM / 2);
#pragma unroll
        for (int j = 0; j < 4; ++j) {
            const size_t idx = (size_t)m * N + (n0 + (j & 1) * 16 + (j >> 1) * 128);
            const f32x4 c = acc[i][j];
            if constexpr (MODE == MODE_T) {
                bf16x4 o;
#pragma unroll
                for (int r = 0; r < 4; ++r) o[r] = (bf16_t)c[r];
                *(bf16x4*)(outH + idx) = o;
            } else if constexpr (MODE == MODE_B) {
                bf16x4 ob, ou;
#pragma unroll
                for (int r = 0; r < 4; ++r) {
                    const float un = 0.1f * c[r];       // u1 = 0.1 b (u0=0 => a0=0)
                    ob[r] = (bf16_t)c[r];
                    ou[r] = (bf16_t)un;
                }
                *(bf16x4*)(bb + idx) = ob;
                *(bf16x4*)(u  + idx) = ou;
            } else if constexpr (MODE == MODE_STEP2) {
                const bf16x4 uv = *(const bf16x4*)(u  + idx);
                const bf16x4 bv = *(const bf16x4*)(bb + idx);
                bf16x4 ou;
#pragma unroll
                for (int r = 0; r < 4; ++r) {
                    const float uo = (float)uv[r];
                    const float ao = fmaxf(uo - 0.1f, 0.f);    // a_old from u_old
                    const float un = 0.9f * uo + 0.1f * (float)bv[r]
                                   - 0.1f * c[r] + 0.1f * ao * gvv[j][r];
                    ou[r] = (bf16_t)un;
                }
                *(bf16x4*)(u + idx) = ou;
            } else { // MODE_OUT
                *(f32x4*)(outF + idx) = c;
            }
        }
    }
}

__global__ void cast_x_kernel(const float* __restrict__ x, bf16_t* __restrict__ xh, int n) {
    int i = (blockIdx.x * 256 + threadIdx.x) * 4;
    if (i < n) {
        f32x4 v = *(const f32x4*)(x + i);
        bf16x4 o;
#pragma unroll
        for (int r = 0; r < 4; ++r) o[r] = (bf16_t)v[r];
        *(bf16x4*)(xh + i) = o;
    }
}

// Wh = bf16(W) [1024][4096] ; WT = bf16(W^T) [4096][1024] via LDS-tiled transpose.
// Tile: 64 k-rows x 128 n-cols. Read coalesced (512B/row-pass); WT write contiguous
// per n-row. [64][130] pad -> bank = (65*kk)&31 = kk%32, conflict-free.
__global__ void prep_w_kernel(const float* __restrict__ W,
                              bf16_t* __restrict__ Wh, bf16_t* __restrict__ WT) {
    __shared__ bf16_t tile[64][130];
    const int k0 = blockIdx.y * 64;     // gridDim.y = 16
    const int n0 = blockIdx.x * 128;    // gridDim.x = 32
    for (int e = threadIdx.x; e < 64 * 128; e += 256) {
        const int kk = e >> 7, nn = e & 127;
        const bf16_t v = (bf16_t)W[(size_t)(k0 + kk) * 4096 + n0 + nn];
        Wh[(size_t)(k0 + kk) * 4096 + n0 + nn] = v;
        tile[kk][nn] = v;
    }
    __syncthreads();
    for (int e = threadIdx.x; e < 64 * 128; e += 256) {
        const int nn = e >> 6, kk = e & 63;
        WT[(size_t)(n0 + nn) * 1024 + k0 + kk] = tile[kk][nn];
    }
}

__global__ void zero_g_kernel(float* __restrict__ g) {
    int i = blockIdx.x * 256 + threadIdx.x;
    if (i < 4096) g[i] = 0.f;
}

// g[j] = sum_k W[k][j]^2 — 128 blocks of partial sums + atomicAdd (coalesced j).
__global__ void prep_g_kernel(const float* __restrict__ W, float* __restrict__ g) {
    const int j  = blockIdx.x * 256 + threadIdx.x;   // gridDim.x = 16
    const int k0 = blockIdx.y * 128;                 // gridDim.y = 8
    float s = 0.f;
    for (int k = k0; k < k0 + 128; ++k) {
        const float v = W[(size_t)k * 4096 + j];
        s += v * v;
    }
    atomicAdd(g + j, s);
}

extern "C" void kernel_launch(void* const* d_in, const int* in_sizes, int n_in,
                              void* d_out, int out_size, void* d_ws, size_t ws_size,
                              hipStream_t stream)
{
    const float* x = (const float*)d_in[0];   // [8192][1024]
    const float* W = (const float*)d_in[1];   // [1024][4096]

    // d_out doubles as scratch until the final GEMM writes it:
    //   [0,16MiB): xh (bf16 x) until b-GEMM, then t ; [16MiB,+16KiB): g
    bf16_t* xh = (bf16_t*)d_out;
    bf16_t* tt = (bf16_t*)d_out;
    float*  gd = (float*)((char*)d_out + 16777216);

    char* ws = (char*)d_ws;                   // (a-slot unused; layout kept)
    bf16_t* bb = (bf16_t*)(ws + 67108864);    //  64 MiB [8192][4096]
    bf16_t* u  = (bf16_t*)(ws + 134217728);   //  64 MiB [8192][4096]
    bf16_t* Wh = (bf16_t*)(ws + 201326592);   //   8 MiB [1024][4096]
    bf16_t* WT = (bf16_t*)(ws + 209715200);   //   8 MiB [4096][1024]

    cast_x_kernel<<<8388608 / 1024, 256, 0, stream>>>(x, xh, 8388608);
    prep_w_kernel<<<dim3(32, 16), 256, 0, stream>>>(W, Wh, WT);
    zero_g_kernel<<<16, 256, 0, stream>>>(gd);
    prep_g_kernel<<<dim3(16, 8), 256, 0, stream>>>(W, gd);

    // b = x@W ; u1 = 0.1b.  A=xh, Bt=WT, N=4096, K=1024
    gemm_bt<MODE_B, 256><<<dim3(16, 32), 512, 0, stream>>>(xh, WT, 4096, 1024,
                                                           nullptr, nullptr, bb, u, nullptr);
    // 9 remaining steps: t = relu(u)@W^T (BM=128, A=u) ; s = t@W fused update (BM=256)
    for (int s = 0; s < 9; ++s) {
        gemm_bt<MODE_T, 128><<<dim3(4, 64), 512, 0, stream>>>(u, Wh, 1024, 4096,
                                                              nullptr, tt, nullptr, nullptr, nullptr);
        gemm_bt<MODE_STEP2, 256><<<dim3(16, 32), 512, 0, stream>>>(tt, WT, 4096, 1024,
                                                                   nullptr, nullptr, bb, u, gd);
    }
    // out = relu(u)@W^T : A=u, Bt=Wh, N=1024, K=4096, fp32 into d_out
    gemm_bt<MODE_OUT, 128><<<dim3(4, 64), 512, 0, stream>>>(u, Wh, 1024, 4096,
                                                            (float*)d_out, nullptr, nullptr, nullptr, nullptr);
}

// Round 5
// 1714.709 us; speedup vs baseline: 1.3165x; 1.0350x over previous
//
#include <hip/hip_runtime.h>
#include <hip/hip_bf16.h>

// LCA layer on MI355X — rank-factored steps, counted-vmcnt GEMM cores with
// one-phase ds_read lookahead; no materialized `a` (relu(u-0.1) recomputed).
//   b = x@W ; g[j] = sum_k W[k][j]^2
//   u1 = 0.1 b
//   per step: t = relu(u-.1)@W^T ; s = t@W ; u' = 0.9u + 0.1b - 0.1s + 0.1*relu(u-.1)*g
//   out = relu(u-.1)@W^T (fp32)
//
// BM=256 (B/STEP2): ring-of-2 BK=64. Register-neutral partial pipeline: B-q1
//   fragments read at P0 (covered by P0's vmcnt(4) — FIFO: retire B01,A01,B23),
//   so P1 needs no wait/barrier. 2 barriers/tile (was 3), exposed ds-gates at
//   M0 and M2 only. Waits: main {P0:4, P2:4}, tail {2, 0}. Slot-XOR swizzle
//   (0 bank conflicts measured). Epilogue writes only u (+bb in MODE_B).
// BM=128 (T/OUT): A = relu(u) reg-bounced into double-buffered As; FULL
//   one-phase lookahead — each MFMA group's fragments are ds_read one phase
//   before use (M3 of tile k issues after Ph_A(k+1)'s bar+reads):
//     Ph_B: stage B01' ; vmcnt{4,2,0} ; bar ; read B-q1 ; M0
//     Ph_C: stage B23' ; read A-q1 ; relu+ds_write A' ; M1
//     Ph_D: lgkmcnt(0) (drain A' writes) ; M2
//     Ph_A(k+1): vmcnt(2) ; bar ; rotate A-regs ; issue A-regs(k+3) ;
//                read next A-q0 + B-q0 (alt bf0 bank) ; M3(k)
//   Zero exposed ds-latency in steady state. bf0 double-banked via 2-unrolled
//   tile loop (static indexing — no scratch). ~184 regs -> 2 waves/SIMD kept.
// Operand swap retained: lane's 4 acc regs = 4 consecutive output cols at one row.
// Bijective XCD-chunk swizzle on block index (nwg % 8 == 0 for all grids).

typedef __bf16 bf16_t;
typedef __bf16 bf16x8 __attribute__((ext_vector_type(8)));
typedef __bf16 bf16x4 __attribute__((ext_vector_type(4)));
typedef float  f32x4  __attribute__((ext_vector_type(4)));

__device__ __forceinline__ void g2lds16(const void* g, void* l) {
    __builtin_amdgcn_global_load_lds(
        (const __attribute__((address_space(1))) void*)g,
        (__attribute__((address_space(3))) void*)l,
        16, 0, 0);
}

template<int N> __device__ __forceinline__ void waitv() {
    if constexpr (N == 0) asm volatile("s_waitcnt vmcnt(0)" ::: "memory");
    else if constexpr (N == 1) asm volatile("s_waitcnt vmcnt(1)" ::: "memory");
    else if constexpr (N == 2) asm volatile("s_waitcnt vmcnt(2)" ::: "memory");
    else if constexpr (N == 3) asm volatile("s_waitcnt vmcnt(3)" ::: "memory");
    else if constexpr (N == 4) asm volatile("s_waitcnt vmcnt(4)" ::: "memory");
    else if constexpr (N == 5) asm volatile("s_waitcnt vmcnt(5)" ::: "memory");
    else if constexpr (N == 6) asm volatile("s_waitcnt vmcnt(6)" ::: "memory");
}
__device__ __forceinline__ void bar() { __builtin_amdgcn_s_barrier(); }
__device__ __forceinline__ void waitlgkm0() {
    asm volatile("s_waitcnt lgkmcnt(0)" ::: "memory");
}
__device__ __forceinline__ void fence() { asm volatile("" ::: "memory"); }

template<int n> struct IC { static constexpr int v = n; };

enum { MODE_B = 0, MODE_T = 1, MODE_STEP2 = 2, MODE_OUT = 3 };

// C[m][n] = sum_k A[m][k] * Bt[n][k]  (A:[M][K], Bt:[N][K], bf16, K%64==0).
// Grid: x covers N in 256-tiles, y covers M in BM-tiles. 512 threads.
template<int MODE, int BM>
__global__ __launch_bounds__(512, 2)
void gemm_bt(const bf16_t* __restrict__ A, const bf16_t* __restrict__ Bt,
             int N, int K,
             float*  __restrict__ outF,   // MODE_OUT: final fp32 output
             bf16_t* __restrict__ outH,   // MODE_T: t
             bf16_t* __restrict__ bb,     // MODE_B: write b ; MODE_STEP2: read b
             bf16_t* __restrict__ u,      // MODE_B: write u ; MODE_STEP2: rmw u
             const float* __restrict__ g) // MODE_STEP2: diag(W^T W), [N]
{
    constexpr int BN  = 256;
    constexpr int FM  = BM / 32;       // 8 (BM=256) or 4 (BM=128)
    constexpr int FMH = FM / 2;        // fragments per A-slice: 4 or 2
    constexpr int ASZ = BM * 128;      // bytes per A slot
    constexpr int BSZ = BN * 128;      // bytes per B slot

    __shared__ __attribute__((aligned(16))) bf16_t As[2 * BM * 64];
    __shared__ __attribute__((aligned(16))) bf16_t Bs[2 * BN * 64];

    const int t = threadIdx.x;
    const int l = t & 63;
    const int w = t >> 6;
    const int wm = (w >> 2) * (BM / 4);   // {0, BM/4}
    const int wn = (w & 3) * 32;          // {0,32,64,96}

    // bijective XCD-chunk swizzle (nwg % 8 == 0 for all our grids)
    const int gx  = gridDim.x;
    const int nwg = gx * gridDim.y;
    const int bid = blockIdx.y * gx + blockIdx.x;
    const int sw  = (bid & 7) * (nwg >> 3) + (bid >> 3);
    const int rowA = (sw / gx) * BM;
    const int colB = (sw % gx) * BN;

    // ---- B staging (linear LDS dest, inverse-swizzled global source) ----
    const int srow = t >> 3;
    const int scol = (((t & 7) ^ (srow & 7)) << 3);
    const bf16_t* gB = Bt + (size_t)(colB + srow) * K + scol;
    char* sB = (char*)Bs + t * 16;
    auto stB = [&](int slot, int kt, int uu) {
        g2lds16(gB + (size_t)uu * 64 * K + kt * 64, sB + slot * BSZ + uu * 8192);
    };

    // ---- fragment reads (swizzled address) ----
    const int lrow = l & 15;
    const int c0 = ((l >> 4) << 4) ^ ((l & 7) << 4);
    const char* cAs = (const char*)As;
    const char* cBs = (const char*)Bs;
    auto rdA = [&](int slot, int qi, int ii, int p) {
        return (const bf16x8*)(cAs + slot * ASZ
            + (size_t)(qi * (BM / 2) + wm + ii * 16 + lrow) * 128 + (c0 ^ (p << 6)));
    };
    auto rdB = [&](int slot, int qj, int jj, int p) {
        return (const bf16x8*)(cBs + slot * BSZ
            + (size_t)(qj * 128 + wn + jj * 16 + lrow) * 128 + (c0 ^ (p << 6)));
    };

    f32x4 acc[FM][4];
#pragma unroll
    for (int i = 0; i < FM; ++i)
#pragma unroll
        for (int j = 0; j < 4; ++j)
#pragma unroll
            for (int r = 0; r < 4; ++r) acc[i][j][r] = 0.f;

    const int NT = K >> 6;

    if constexpr (BM == 256) {
        // -------- B/STEP2 core: partial pipeline (B-q1 read at P0) --------
        const bf16_t* gA = A + (size_t)(rowA + srow) * K + scol;
        char* sA = (char*)As + t * 16;
        auto stA = [&](int slot, int kt, int uu) {
            g2lds16(gA + (size_t)uu * 64 * K + kt * 64, sA + slot * ASZ + uu * 8192);
        };

        auto MQ = [&](int qi, int qj, bf16x8 (&Af)[FMH][2], bf16x8 (&Bf)[2][2]) {
            __builtin_amdgcn_s_setprio(1);
#pragma unroll
            for (int ii = 0; ii < FMH; ++ii)
#pragma unroll
                for (int jj = 0; jj < 2; ++jj)
#pragma unroll
                    for (int p = 0; p < 2; ++p)
                        acc[qi * FMH + ii][qj * 2 + jj] =
                            __builtin_amdgcn_mfma_f32_16x16x32_bf16(
                                Bf[jj][p], Af[ii][p],
                                acc[qi * FMH + ii][qj * 2 + jj], 0, 0, 0);
            __builtin_amdgcn_s_setprio(0);
        };

        auto tile = [&](auto W0, auto W2, int slot, int ktN, bool st) {
            const int ns = slot ^ 1;
            bf16x8 af[FMH][2], bfA[2][2], bfB[2][2];
            // P0: stage B01(next); wait; bar; read A-q0 + B-q0 + B-q1; MFMA (0,0)
            if (st) { stB(ns, ktN, 0); stB(ns, ktN, 1); }
            waitv<decltype(W0)::v>(); bar();
#pragma unroll
            for (int ii = 0; ii < FMH; ++ii)
#pragma unroll
                for (int p = 0; p < 2; ++p) af[ii][p] = *rdA(slot, 0, ii, p);
#pragma unroll
            for (int jj = 0; jj < 2; ++jj)
#pragma unroll
                for (int p = 0; p < 2; ++p) bfA[jj][p] = *rdB(slot, 0, jj, p);
#pragma unroll
            for (int jj = 0; jj < 2; ++jj)
#pragma unroll
                for (int p = 0; p < 2; ++p) bfB[jj][p] = *rdB(slot, 1, jj, p);
            MQ(0, 0, af, bfA);
            // P1: stage A01(next); MFMA (0,1)  [no wait, no barrier]
            if (st) { stA(ns, ktN, 0); stA(ns, ktN, 1); }
            MQ(0, 1, af, bfB);
            // P2: stage B23(next); wait; bar; read A-q1; MFMA (1,1)
            if (st) { stB(ns, ktN, 2); stB(ns, ktN, 3); }
            waitv<decltype(W2)::v>(); bar();
#pragma unroll
            for (int ii = 0; ii < FMH; ++ii)
#pragma unroll
                for (int p = 0; p < 2; ++p) af[ii][p] = *rdA(slot, 1, ii, p);
            MQ(1, 1, af, bfB);
            // P3: stage A23(next); MFMA (1,0)
            if (st) { stA(ns, ktN, 2); stA(ns, ktN, 3); }
            MQ(1, 0, af, bfA);
        };

        // prologue: stage tile 0 in issue order B0,A0,B1,A1 (FIFO invariant)
        stB(0, 0, 0); stB(0, 0, 1);
        stA(0, 0, 0); stA(0, 0, 1);
        stB(0, 0, 2); stB(0, 0, 3);
        stA(0, 0, 2); stA(0, 0, 3);

        for (int kt = 0; kt < NT - 1; ++kt)
            tile(IC<4>{}, IC<4>{}, kt & 1, kt + 1, true);
        tile(IC<2>{}, IC<0>{}, (NT - 1) & 1, 0, false);
    } else {
        // -------- T/OUT core: full one-phase lookahead, A = relu(u) --------
        const int s_arow = t >> 3;
        const int s_acb  = ((t & 7) << 4) ^ ((s_arow & 7) << 4);
        const bf16_t* gAr = A + (size_t)(rowA + s_arow) * K + (t & 7) * 8;
        auto reluv = [&](bf16x8 v) {
            bf16x8 r;
#pragma unroll
            for (int e = 0; e < 8; ++e)
                r[e] = (bf16_t)fmaxf((float)v[e] - 0.1f, 0.f);
            return r;
        };
        auto wrA = [&](bf16x8 v, int gg, int slot) {
            *(bf16x8*)((char*)As + slot * ASZ
                       + (size_t)(gg * 64 + s_arow) * 128 + s_acb) = v;
        };

        auto MQ = [&](int qi, int qj, bf16x8 (&Af)[FMH][2], bf16x8 (&Bf)[2][2]) {
            __builtin_amdgcn_s_setprio(1);
#pragma unroll
            for (int ii = 0; ii < FMH; ++ii)
#pragma unroll
                for (int jj = 0; jj < 2; ++jj)
#pragma unroll
                    for (int p = 0; p < 2; ++p)
                        acc[qi * FMH + ii][qj * 2 + jj] =
                            __builtin_amdgcn_mfma_f32_16x16x32_bf16(
                                Bf[jj][p], Af[ii][p],
                                acc[qi * FMH + ii][qj * 2 + jj], 0, 0, 0);
            __builtin_amdgcn_s_setprio(0);
        };

        bf16x8 af0[FMH][2], af1[FMH][2], bf1v[2][2], bf0A[2][2], bf0B[2][2];
        bf16x8 curA0, curA1, nA0, nA1;

        // prologue: A(0)->LDS slot0; A-regs(1); B(0)x4; peeled Ph_A(0)
        {
            bf16x8 p0 = *(const bf16x8*)(gAr);
            bf16x8 p1 = *(const bf16x8*)(gAr + (size_t)64 * K);
            waitv<0>();
            wrA(reluv(p0), 0, 0);
            wrA(reluv(p1), 1, 0);
            waitlgkm0();
            curA0 = *(const bf16x8*)(gAr + 64);
            curA1 = *(const bf16x8*)(gAr + (size_t)64 * K + 64);
            fence();
            stB(0, 0, 0); stB(0, 0, 1); stB(0, 0, 2); stB(0, 0, 3);
            // Ph_A(0): FIFO [Areg(1)2, B(0)01 2, B(0)23 2] -> retire 4
            waitv<2>(); bar();
            nA0 = *(const bf16x8*)(gAr + 2 * 64);
            nA1 = *(const bf16x8*)(gAr + (size_t)64 * K + 2 * 64);
            fence();
#pragma unroll
            for (int ii = 0; ii < FMH; ++ii)
#pragma unroll
                for (int p = 0; p < 2; ++p) af0[ii][p] = *rdA(0, 0, ii, p);
#pragma unroll
            for (int jj = 0; jj < 2; ++jj)
#pragma unroll
                for (int p = 0; p < 2; ++p) bf0A[jj][p] = *rdB(0, 0, jj, p);
        }

        auto tb = [&](int kt, bf16x8 (&b0c)[2][2], bf16x8 (&b0n)[2][2]) {
            const int slot = kt & 1, ns = slot ^ 1;
            const bool sB = kt + 1 < NT;
            // Ph_B: stage B01(kt+1); wait B23(kt); bar; read B-q1; M0
            if (sB) { stB(ns, kt + 1, 0); stB(ns, kt + 1, 1); }
            if (kt < NT - 2) waitv<4>();
            else if (kt == NT - 2) waitv<2>();
            else waitv<0>();
            bar();
#pragma unroll
            for (int jj = 0; jj < 2; ++jj)
#pragma unroll
                for (int p = 0; p < 2; ++p) bf1v[jj][p] = *rdB(slot, 1, jj, p);
            MQ(0, 0, af0, b0c);
            // Ph_C: stage B23(kt+1); read A-q1; relu+write A(kt+1); M1
            if (sB) { stB(ns, kt + 1, 2); stB(ns, kt + 1, 3); }
#pragma unroll
            for (int ii = 0; ii < FMH; ++ii)
#pragma unroll
                for (int p = 0; p < 2; ++p) af1[ii][p] = *rdA(slot, 1, ii, p);
            if (sB) { wrA(reluv(curA0), 0, ns); wrA(reluv(curA1), 1, ns); }
            MQ(0, 1, af0, bf1v);
            // Ph_D: drain ds_writes (visibility before Ph_A's bar); M2
            waitlgkm0();
            MQ(1, 1, af1, bf1v);
            // Ph_A(kt+1): wait; bar; rotate A-regs; issue A-regs(kt+3); read next
            if (sB) {
                waitv<2>(); bar();
                curA0 = nA0; curA1 = nA1;
                if (kt + 3 < NT) {
                    nA0 = *(const bf16x8*)(gAr + (size_t)(kt + 3) * 64);
                    nA1 = *(const bf16x8*)(gAr + (size_t)64 * K + (size_t)(kt + 3) * 64);
                    fence();
                }
#pragma unroll
                for (int ii = 0; ii < FMH; ++ii)
#pragma unroll
                    for (int p = 0; p < 2; ++p) af0[ii][p] = *rdA(ns, 0, ii, p);
#pragma unroll
                for (int jj = 0; jj < 2; ++jj)
#pragma unroll
                    for (int p = 0; p < 2; ++p) b0n[jj][p] = *rdB(ns, 0, jj, p);
            }
            MQ(1, 0, af1, b0c);
        };

        for (int kt = 0; kt < NT; kt += 2) {
            tb(kt, bf0A, bf0B);
            tb(kt + 1, bf0B, bf0A);
        }
    }

    // ---- epilogue ----
    // m = rowA + wm + (i&(FMH-1))*16 + (i/FMH)*(BM/2) + (l&15)
    // n = colB + wn + (j&1)*16 + (j>>1)*128 + (l>>4)*4 + r
    const int m0 = rowA + wm + lrow;
    const int n0 = colB + wn + ((l >> 4) * 4);

    f32x4 gvv[4];
    if constexpr (MODE == MODE_STEP2) {
#pragma unroll
        for (int j = 0; j < 4; ++j)
            gvv[j] = *(const f32x4*)(g + n0 + (j & 1) * 16 + (j >> 1) * 128);
    }

#pragma unroll
    for (int i = 0; i < FM; ++i) {
        const int m = m0 + (i & (FMH - 1)) * 16 + (i / FMH) * (BM / 2);
#pragma unroll
        for (int j = 0; j < 4; ++j) {
            const size_t idx = (size_t)m * N + (n0 + (j & 1) * 16 + (j >> 1) * 128);
            const f32x4 c = acc[i][j];
            if constexpr (MODE == MODE_T) {
                bf16x4 o;
#pragma unroll
                for (int r = 0; r < 4; ++r) o[r] = (bf16_t)c[r];
                *(bf16x4*)(outH + idx) = o;
            } else if constexpr (MODE == MODE_B) {
                bf16x4 ob, ou;
#pragma unroll
                for (int r = 0; r < 4; ++r) {
                    const float un = 0.1f * c[r];       // u1 = 0.1 b (u0=0 => a0=0)
                    ob[r] = (bf16_t)c[r];
                    ou[r] = (bf16_t)un;
                }
                *(bf16x4*)(bb + idx) = ob;
                *(bf16x4*)(u  + idx) = ou;
            } else if constexpr (MODE == MODE_STEP2) {
                const bf16x4 uv = *(const bf16x4*)(u  + idx);
                const bf16x4 bv = *(const bf16x4*)(bb + idx);
                bf16x4 ou;
#pragma unroll
                for (int r = 0; r < 4; ++r) {
                    const float uo = (float)uv[r];
                    const float ao = fmaxf(uo - 0.1f, 0.f);    // a_old from u_old
                    const float un = 0.9f * uo + 0.1f * (float)bv[r]
                                   - 0.1f * c[r] + 0.1f * ao * gvv[j][r];
                    ou[r] = (bf16_t)un;
                }
                *(bf16x4*)(u + idx) = ou;
            } else { // MODE_OUT
                *(f32x4*)(outF + idx) = c;
            }
        }
    }
}

__global__ void cast_x_kernel(const float* __restrict__ x, bf16_t* __restrict__ xh, int n) {
    int i = (blockIdx.x * 256 + threadIdx.x) * 4;
    if (i < n) {
        f32x4 v = *(const f32x4*)(x + i);
        bf16x4 o;
#pragma unroll
        for (int r = 0; r < 4; ++r) o[r] = (bf16_t)v[r];
        *(bf16x4*)(xh + i) = o;
    }
}

// Wh = bf16(W) [1024][4096] ; WT = bf16(W^T) [4096][1024] via LDS-tiled transpose.
__global__ void prep_w_kernel(const float* __restrict__ W,
                              bf16_t* __restrict__ Wh, bf16_t* __restrict__ WT) {
    __shared__ bf16_t tile[64][130];
    const int k0 = blockIdx.y * 64;     // gridDim.y = 16
    const int n0 = blockIdx.x * 128;    // gridDim.x = 32
    for (int e = threadIdx.x; e < 64 * 128; e += 256) {
        const int kk = e >> 7, nn = e & 127;
        const bf16_t v = (bf16_t)W[(size_t)(k0 + kk) * 4096 + n0 + nn];
        Wh[(size_t)(k0 + kk) * 4096 + n0 + nn] = v;
        tile[kk][nn] = v;
    }
    __syncthreads();
    for (int e = threadIdx.x; e < 64 * 128; e += 256) {
        const int nn = e >> 6, kk = e & 63;
        WT[(size_t)(n0 + nn) * 1024 + k0 + kk] = tile[kk][nn];
    }
}

__global__ void zero_g_kernel(float* __restrict__ g) {
    int i = blockIdx.x * 256 + threadIdx.x;
    if (i < 4096) g[i] = 0.f;
}

// g[j] = sum_k W[k][j]^2 — 128 blocks of partial sums + atomicAdd (coalesced j).
__global__ void prep_g_kernel(const float* __restrict__ W, float* __restrict__ g) {
    const int j  = blockIdx.x * 256 + threadIdx.x;   // gridDim.x = 16
    const int k0 = blockIdx.y * 128;                 // gridDim.y = 8
    float s = 0.f;
    for (int k = k0; k < k0 + 128; ++k) {
        const float v = W[(size_t)k * 4096 + j];
        s += v * v;
    }
    atomicAdd(g + j, s);
}

extern "C" void kernel_launch(void* const* d_in, const int* in_sizes, int n_in,
                              void* d_out, int out_size, void* d_ws, size_t ws_size,
                              hipStream_t stream)
{
    const float* x = (const float*)d_in[0];   // [8192][1024]
    const float* W = (const float*)d_in[1];   // [1024][4096]

    // d_out doubles as scratch until the final GEMM writes it:
    //   [0,16MiB): xh (bf16 x) until b-GEMM, then t ; [16MiB,+16KiB): g
    bf16_t* xh = (bf16_t*)d_out;
    bf16_t* tt = (bf16_t*)d_out;
    float*  gd = (float*)((char*)d_out + 16777216);

    char* ws = (char*)d_ws;                   // (a-slot unused; layout kept)
    bf16_t* bb = (bf16_t*)(ws + 67108864);    //  64 MiB [8192][4096]
    bf16_t* u  = (bf16_t*)(ws + 134217728);   //  64 MiB [8192][4096]
    bf16_t* Wh = (bf16_t*)(ws + 201326592);   //   8 MiB [1024][4096]
    bf16_t* WT = (bf16_t*)(ws + 209715200);   //   8 MiB [4096][1024]

    cast_x_kernel<<<8388608 / 1024, 256, 0, stream>>>(x, xh, 8388608);
    prep_w_kernel<<<dim3(32, 16), 256, 0, stream>>>(W, Wh, WT);
    zero_g_kernel<<<16, 256, 0, stream>>>(gd);
    prep_g_kernel<<<dim3(16, 8), 256, 0, stream>>>(W, gd);

    // b = x@W ; u1 = 0.1b.  A=xh, Bt=WT, N=4096, K=1024
    gemm_bt<MODE_B, 256><<<dim3(16, 32), 512, 0, stream>>>(xh, WT, 4096, 1024,
                                                           nullptr, nullptr, bb, u, nullptr);
    // 9 remaining steps: t = relu(u)@W^T (BM=128, A=u) ; s = t@W fused update (BM=256)
    for (int s = 0; s < 9; ++s) {
        gemm_bt<MODE_T, 128><<<dim3(4, 64), 512, 0, stream>>>(u, Wh, 1024, 4096,
                                                              nullptr, tt, nullptr, nullptr, nullptr);
        gemm_bt<MODE_STEP2, 256><<<dim3(16, 32), 512, 0, stream>>>(tt, WT, 4096, 1024,
                                                                   nullptr, nullptr, bb, u, gd);
    }
    // out = relu(u)@W^T : A=u, Bt=Wh, N=1024, K=4096, fp32 into d_out
    gemm_bt<MODE_OUT, 128><<<dim3(4, 64), 512, 0, stream>>>(u, Wh, 1024, 4096,
                                                            (float*)d_out, nullptr, nullptr, nullptr, nullptr);
}